// Round 2
// baseline (455.357 us; speedup 1.0000x reference)
//
#include <hip/hip_runtime.h>
#include <hip/hip_bf16.h>
#include <stdint.h>

#define BB 2
#define SS 2048
#define DDIM 1024
#define HH 16
#define HDIM 64

typedef __hip_bfloat16 bf16;
typedef __bf16 bf16x8 __attribute__((ext_vector_type(8)));
typedef float f32x4 __attribute__((ext_vector_type(4)));
typedef short short8 __attribute__((ext_vector_type(8)));

static __device__ __forceinline__ f32x4 mfma16(bf16x8 a, bf16x8 b, f32x4 c) {
  return __builtin_amdgcn_mfma_f32_16x16x32_bf16(a, b, c, 0, 0, 0);
}

static __device__ __forceinline__ void gload_lds16(const void* g, void* l) {
  __builtin_amdgcn_global_load_lds(
      (const __attribute__((address_space(1))) void*)g,
      (__attribute__((address_space(3))) void*)l, 16, 0, 0);
}

// ---------------- f32 -> bf16 flat convert (8 elems/thread) ----------------
__global__ __launch_bounds__(256) void cvt_k(const float* __restrict__ src,
                                             bf16* __restrict__ dst) {
  const int base = (blockIdx.x * 256 + threadIdx.x) * 8;
  float4 a = *reinterpret_cast<const float4*>(src + base);
  float4 b = *reinterpret_cast<const float4*>(src + base + 4);
  union {
    bf16 h[8];
    short8 v;
  } u;
  u.h[0] = __float2bfloat16(a.x);
  u.h[1] = __float2bfloat16(a.y);
  u.h[2] = __float2bfloat16(a.z);
  u.h[3] = __float2bfloat16(a.w);
  u.h[4] = __float2bfloat16(b.x);
  u.h[5] = __float2bfloat16(b.y);
  u.h[6] = __float2bfloat16(b.z);
  u.h[7] = __float2bfloat16(b.w);
  *reinterpret_cast<short8*>(dst + base) = u.v;
}

// ------------- transpose+convert: dst[n][k] = (bf16)src[k][n], 1024x1024 ----
__global__ __launch_bounds__(256) void transpose_cvt_k(
    const float* __restrict__ src, bf16* __restrict__ dst) {
  __shared__ float tile[64][65];
  const int t = threadIdx.x;
  const int r = t >> 2, c0 = (t & 3) * 16;
  const int bx = blockIdx.x * 64, by = blockIdx.y * 64;
  const float* sp = src + (size_t)(by + r) * DDIM + bx + c0;
#pragma unroll
  for (int j = 0; j < 16; ++j) tile[r][c0 + j] = sp[j];
  __syncthreads();
  bf16* dp = dst + (size_t)(bx + r) * DDIM + by + c0;
#pragma unroll
  for (int j = 0; j < 16; ++j) dp[j] = __float2bfloat16(tile[c0 + j][r]);
}

// ---------------- GEMM: C[m][n] = A[m][:] . Bt[n][:]  (row-major, K=1024)
// MODE 0: N=3072, scatter bf16 to Q / K / Vt with per-section f32 bias
// MODE 1: N=1024, write f32 Of[m*1024+n] + bias b0
template <int MODE>
__global__ __launch_bounds__(256, 2) void gemm_bt(
    const bf16* __restrict__ A, const bf16* __restrict__ Bt,
    const float* __restrict__ b0, const float* __restrict__ b1,
    const float* __restrict__ b2, bf16* __restrict__ O0,
    bf16* __restrict__ O1, bf16* __restrict__ O2, float* __restrict__ Of) {
  constexpr int Kd = DDIM;
  __shared__ bf16x8 lA[128 * 8];
  __shared__ bf16x8 lB[128 * 8];
  const int tid = threadIdx.x;
  const int wave = tid >> 6, lane = tid & 63;
  const int l15 = lane & 15, l4 = lane >> 4;
  const int wm = wave >> 1, wn = wave & 1;
  const int m0 = blockIdx.x * 128, n0 = blockIdx.y * 128;
  const f32x4 z = {0.f, 0.f, 0.f, 0.f};
  f32x4 acc[4][4];
#pragma unroll
  for (int i = 0; i < 4; ++i)
#pragma unroll
    for (int j = 0; j < 4; ++j) acc[i][j] = z;

  for (int k0 = 0; k0 < Kd; k0 += 64) {
#pragma unroll
    for (int j = 0; j < 4; ++j) {
      const int slot = j * 256 + tid;
      const int r = slot >> 3, cs = slot & 7;
      const int c = cs ^ (r & 7);  // pre-swizzled global source, linear LDS dest
      gload_lds16(A + (size_t)(m0 + r) * Kd + k0 + c * 8,
                  &lA[j * 256 + wave * 64]);
      gload_lds16(Bt + (size_t)(n0 + r) * Kd + k0 + c * 8,
                  &lB[j * 256 + wave * 64]);
    }
    __syncthreads();
    bf16x8 af[2][4], bfr[2][4];
#pragma unroll
    for (int ks = 0; ks < 2; ++ks) {
#pragma unroll
      for (int i = 0; i < 4; ++i) {
        const int ra = wm * 64 + i * 16 + l15;
        af[ks][i] = lA[ra * 8 + ((ks * 4 + l4) ^ (ra & 7))];
        const int rb = wn * 64 + i * 16 + l15;
        bfr[ks][i] = lB[rb * 8 + ((ks * 4 + l4) ^ (rb & 7))];
      }
    }
#pragma unroll
    for (int ks = 0; ks < 2; ++ks)
#pragma unroll
      for (int i = 0; i < 4; ++i)
#pragma unroll
        for (int j = 0; j < 4; ++j)
          acc[i][j] = mfma16(af[ks][i], bfr[ks][j], acc[i][j]);
    __syncthreads();
  }

  // C row m = m0 + wm*64 + i*16 + l4*4 + r ; col n = n0 + wn*64 + j*16 + l15
#pragma unroll
  for (int i = 0; i < 4; ++i) {
    const int m = m0 + wm * 64 + i * 16 + l4 * 4;
#pragma unroll
    for (int j = 0; j < 4; ++j) {
      const int n = n0 + wn * 64 + j * 16 + l15;
      if (MODE == 1) {
        const float bb = b0[n];
#pragma unroll
        for (int r = 0; r < 4; ++r)
          Of[(size_t)(m + r) * DDIM + n] = acc[i][j][r] + bb;
      } else {
        const int sel = n >> 10, nn = n & 1023;
        const int h = nn >> 6, d = nn & 63;
        const float* bp = sel == 0 ? b0 : (sel == 1 ? b1 : b2);
        const float bb = bp[nn];
        const int b = m >> 11, s = m & 2047;
#pragma unroll
        for (int r = 0; r < 4; ++r) {
          const float val = acc[i][j][r] + bb;
          if (sel == 2)
            O2[((size_t)(b * HH + h) * HDIM + d) * SS + (s + r)] =
                __float2bfloat16(val);
          else
            (sel ? O1 : O0)[((size_t)(b * HH + h) * SS + (s + r)) * HDIM + d] =
                __float2bfloat16(val);
        }
      }
    }
  }
}

// ---------------- fused flash attention ----------------
// grid.x = B*H*(S/64); block = 256 (4 waves), wave owns 16 q-rows
__global__ __launch_bounds__(256, 2) void attn_k(
    const bf16* __restrict__ Qb, const bf16* __restrict__ Kb,
    const bf16* __restrict__ Vt, const float* __restrict__ bias,
    const int* __restrict__ kpm, bf16* __restrict__ ctx) {
  __shared__ bf16x8 pl[4 * 128];  // per-wave 16x64 bf16 P scratch (swizzled)
  const int wave = threadIdx.x >> 6, lane = threadIdx.x & 63;
  const int l15 = lane & 15, l4 = lane >> 4;
  const int bid = blockIdx.x;
  const int qblk = bid & 31, bh = bid >> 5;
  const int b = bh >> 4, h = bh & 15;
  const int q0 = qblk * 64 + wave * 16;

  const bf16* Qp = Qb + ((size_t)bh * SS + q0) * HDIM;
  const bf16* Kp = Kb + (size_t)bh * SS * HDIM;
  const bf16* Vp = Vt + (size_t)bh * HDIM * SS;
  const float* Bp = bias + (size_t)h * SS * SS + (size_t)(q0 + l4 * 4) * SS;
  const int* mp = kpm + b * SS;

  bf16x8 qf[2];
#pragma unroll
  for (int ks = 0; ks < 2; ++ks)
    qf[ks] = *reinterpret_cast<const bf16x8*>(Qp + (size_t)l15 * HDIM +
                                              ks * 32 + l4 * 8);
  const f32x4 z = {0.f, 0.f, 0.f, 0.f};
  f32x4 o[4];
#pragma unroll
  for (int dd = 0; dd < 4; ++dd) o[dd] = z;
  float mrow[4], lrow[4];
#pragma unroll
  for (int r = 0; r < 4; ++r) {
    mrow[r] = -1e30f;
    lrow[r] = 0.f;
  }
  bf16* plb = reinterpret_cast<bf16*>(pl);

  for (int kb = 0; kb < SS; kb += 64) {
    f32x4 sc[4];
#pragma unroll
    for (int jj = 0; jj < 4; ++jj) {
      f32x4 s = z;
#pragma unroll
      for (int ks = 0; ks < 2; ++ks) {
        bf16x8 kf = *reinterpret_cast<const bf16x8*>(
            Kp + (size_t)(kb + jj * 16 + l15) * HDIM + ks * 32 + l4 * 8);
        s = mfma16(qf[ks], kf, s);
      }
      sc[jj] = s;
    }
    float bm[4];
#pragma unroll
    for (int r = 0; r < 4; ++r) bm[r] = -1e30f;
#pragma unroll
    for (int jj = 0; jj < 4; ++jj) {
      const int kc = kb + jj * 16 + l15;
      const bool msk = mp[kc] != 0;
#pragma unroll
      for (int r = 0; r < 4; ++r) {
        float v = msk ? -1e30f
                      : (sc[jj][r] * 0.125f + Bp[(size_t)r * SS + kc]);
        sc[jj][r] = v;
        bm[r] = fmaxf(bm[r], v);
      }
    }
#pragma unroll
    for (int off = 8; off; off >>= 1)
#pragma unroll
      for (int r = 0; r < 4; ++r) bm[r] = fmaxf(bm[r], __shfl_xor(bm[r], off));
    float alpha[4];
#pragma unroll
    for (int r = 0; r < 4; ++r) {
      const float mn = fmaxf(mrow[r], bm[r]);
      alpha[r] = __expf(mrow[r] - mn);
      mrow[r] = mn;
    }
    float ps[4] = {0.f, 0.f, 0.f, 0.f};
#pragma unroll
    for (int jj = 0; jj < 4; ++jj) {
      const int col = jj * 16 + l15;
      const int ch = col >> 3, cb = col & 7;
#pragma unroll
      for (int r = 0; r < 4; ++r) {
        const float p = __expf(sc[jj][r] - mrow[r]);
        ps[r] += p;
        const int q = l4 * 4 + r;
        const int byte = wave * 2048 + q * 128 + ((ch ^ (q & 7)) * 16) + cb * 2;
        plb[byte >> 1] = __float2bfloat16(p);
      }
    }
#pragma unroll
    for (int off = 8; off; off >>= 1)
#pragma unroll
      for (int r = 0; r < 4; ++r) ps[r] += __shfl_xor(ps[r], off);
#pragma unroll
    for (int r = 0; r < 4; ++r) lrow[r] = lrow[r] * alpha[r] + ps[r];

    asm volatile("s_waitcnt lgkmcnt(0)" ::: "memory");
    bf16x8 pf[2];
#pragma unroll
    for (int ks = 0; ks < 2; ++ks)
      pf[ks] = pl[wave * 128 + l15 * 8 + ((ks * 4 + l4) ^ (l15 & 7))];
#pragma unroll
    for (int dd = 0; dd < 4; ++dd) {
#pragma unroll
      for (int r = 0; r < 4; ++r) o[dd][r] *= alpha[r];
#pragma unroll
      for (int ks = 0; ks < 2; ++ks) {
        bf16x8 vf = *reinterpret_cast<const bf16x8*>(
            Vp + (size_t)(dd * 16 + l15) * SS + kb + ks * 32 + l4 * 8);
        o[dd] = mfma16(pf[ks], vf, o[dd]);
      }
    }
  }
#pragma unroll
  for (int dd = 0; dd < 4; ++dd) {
#pragma unroll
    for (int r = 0; r < 4; ++r) {
      const float val = o[dd][r] / lrow[r];
      const int s = q0 + l4 * 4 + r;
      ctx[((size_t)b * SS + s) * DDIM + h * HDIM + dd * 16 + l15] =
          __float2bfloat16(val);
    }
  }
}

extern "C" void kernel_launch(void* const* d_in, const int* in_sizes, int n_in,
                              void* d_out, int out_size, void* d_ws,
                              size_t ws_size, hipStream_t stream) {
  const float* x = (const float*)d_in[0];
  const float* abias = (const float*)d_in[1];
  const int* kpm = (const int*)d_in[2];
  const float* Wq = (const float*)d_in[3];
  const float* bq = (const float*)d_in[4];
  const float* Wk = (const float*)d_in[5];
  const float* bk = (const float*)d_in[6];
  const float* Wv = (const float*)d_in[7];
  const float* bv = (const float*)d_in[8];
  const float* Wo = (const float*)d_in[9];
  const float* bo = (const float*)d_in[10];
  float* out = (float*)d_out;

  char* ws = (char*)d_ws;
  bf16* xb = (bf16*)ws;                        // (B,S,D) bf16      8 MB
  bf16* Wt = (bf16*)(ws + 8388608);            // 3072x1024 bf16    6 MB
  bf16* Wot = (bf16*)(ws + 14680064);          // 1024x1024 bf16    2 MB
  bf16* Qb = (bf16*)(ws + 16777216);           // (B,H,S,HD)        8 MB
  bf16* Kb = (bf16*)(ws + 25165824);           // (B,H,S,HD)        8 MB
  bf16* Vtb = (bf16*)(ws + 33554432);          // (B,H,HD,S)        8 MB
  bf16* ctx = (bf16*)(ws + 41943040);          // (B,S,D) bf16      8 MB

  dim3 t256(256);
  cvt_k<<<dim3(2048), t256, 0, stream>>>(x, xb);
  transpose_cvt_k<<<dim3(16, 16), t256, 0, stream>>>(Wq, Wt);
  transpose_cvt_k<<<dim3(16, 16), t256, 0, stream>>>(Wk, Wt + 1024 * 1024);
  transpose_cvt_k<<<dim3(16, 16), t256, 0, stream>>>(Wv, Wt + 2 * 1024 * 1024);
  transpose_cvt_k<<<dim3(16, 16), t256, 0, stream>>>(Wo, Wot);

  gemm_bt<0><<<dim3(32, 24), t256, 0, stream>>>(xb, Wt, bq, bk, bv, Qb, Kb,
                                                Vtb, nullptr);
  attn_k<<<dim3(1024), t256, 0, stream>>>(Qb, Kb, Vtb, abias, kpm, ctx);
  gemm_bt<1><<<dim3(32, 8), t256, 0, stream>>>(ctx, Wot, bo, nullptr, nullptr,
                                               nullptr, nullptr, nullptr, out);
}

// Round 4
// 443.978 us; speedup vs baseline: 1.0256x; 1.0256x over previous
//
#include <hip/hip_runtime.h>
#include <hip/hip_bf16.h>
#include <stdint.h>

#define BB 2
#define SS 2048
#define DDIM 1024
#define HH 16
#define HDIM 64

typedef __hip_bfloat16 bf16;
typedef __bf16 bf16x8 __attribute__((ext_vector_type(8)));
typedef float f32x4 __attribute__((ext_vector_type(4)));
typedef short short8 __attribute__((ext_vector_type(8)));
typedef short s16x4 __attribute__((ext_vector_type(4)));

static __device__ __forceinline__ f32x4 mfma16(bf16x8 a, bf16x8 b, f32x4 c) {
  return __builtin_amdgcn_mfma_f32_16x16x32_bf16(a, b, c, 0, 0, 0);
}

static __device__ __forceinline__ void gload_lds16(const void* g, void* l) {
  __builtin_amdgcn_global_load_lds(
      (const __attribute__((address_space(1))) void*)g,
      (__attribute__((address_space(3))) void*)l, 16, 0, 0);
}

// ---------------- f32 -> bf16 flat convert (8 elems/thread) ----------------
__global__ __launch_bounds__(256) void cvt_k(const float* __restrict__ src,
                                             bf16* __restrict__ dst) {
  const int base = (blockIdx.x * 256 + threadIdx.x) * 8;
  float4 a = *reinterpret_cast<const float4*>(src + base);
  float4 b = *reinterpret_cast<const float4*>(src + base + 4);
  union {
    bf16 h[8];
    short8 v;
  } u;
  u.h[0] = __float2bfloat16(a.x);
  u.h[1] = __float2bfloat16(a.y);
  u.h[2] = __float2bfloat16(a.z);
  u.h[3] = __float2bfloat16(a.w);
  u.h[4] = __float2bfloat16(b.x);
  u.h[5] = __float2bfloat16(b.y);
  u.h[6] = __float2bfloat16(b.z);
  u.h[7] = __float2bfloat16(b.w);
  *reinterpret_cast<short8*>(dst + base) = u.v;
}

// ------------- transpose+convert: dst[n][k] = (bf16)src[k][n], 1024x1024 ----
__global__ __launch_bounds__(256) void transpose_cvt_k(
    const float* __restrict__ src, bf16* __restrict__ dst) {
  __shared__ float tile[64][65];
  const int t = threadIdx.x;
  const int r = t >> 2, c0 = (t & 3) * 16;
  const int bx = blockIdx.x * 64, by = blockIdx.y * 64;
  const float* sp = src + (size_t)(by + r) * DDIM + bx + c0;
#pragma unroll
  for (int j = 0; j < 16; ++j) tile[r][c0 + j] = sp[j];
  __syncthreads();
  bf16* dp = dst + (size_t)(bx + r) * DDIM + by + c0;
#pragma unroll
  for (int j = 0; j < 16; ++j) dp[j] = __float2bfloat16(tile[c0 + j][r]);
}

// ---------------- GEMM: C[m][n] = A[m][:] . Bt[n][:]  (row-major, K=1024)
// MODE 0: N=3072, scatter bf16 to Q / K / Vt with per-section f32 bias
// MODE 1: N=1024, write f32 Of[m*1024+n] + bias b0
template <int MODE>
__global__ __launch_bounds__(256, 2) void gemm_bt(
    const bf16* __restrict__ A, const bf16* __restrict__ Bt,
    const float* __restrict__ b0, const float* __restrict__ b1,
    const float* __restrict__ b2, bf16* __restrict__ O0,
    bf16* __restrict__ O1, bf16* __restrict__ O2, float* __restrict__ Of) {
  constexpr int Kd = DDIM;
  __shared__ bf16x8 lA[128 * 8];
  __shared__ bf16x8 lB[128 * 8];
  const int tid = threadIdx.x;
  const int wave = tid >> 6, lane = tid & 63;
  const int l15 = lane & 15, l4 = lane >> 4;
  const int wm = wave >> 1, wn = wave & 1;
  const int m0 = blockIdx.x * 128, n0 = blockIdx.y * 128;
  const f32x4 z = {0.f, 0.f, 0.f, 0.f};
  f32x4 acc[4][4];
#pragma unroll
  for (int i = 0; i < 4; ++i)
#pragma unroll
    for (int j = 0; j < 4; ++j) acc[i][j] = z;

  for (int k0 = 0; k0 < Kd; k0 += 64) {
#pragma unroll
    for (int j = 0; j < 4; ++j) {
      const int slot = j * 256 + tid;
      const int r = slot >> 3, cs = slot & 7;
      const int c = cs ^ (r & 7);  // pre-swizzled global source, linear LDS dest
      gload_lds16(A + (size_t)(m0 + r) * Kd + k0 + c * 8,
                  &lA[j * 256 + wave * 64]);
      gload_lds16(Bt + (size_t)(n0 + r) * Kd + k0 + c * 8,
                  &lB[j * 256 + wave * 64]);
    }
    __syncthreads();
    bf16x8 af[2][4], bfr[2][4];
#pragma unroll
    for (int ks = 0; ks < 2; ++ks) {
#pragma unroll
      for (int i = 0; i < 4; ++i) {
        const int ra = wm * 64 + i * 16 + l15;
        af[ks][i] = lA[ra * 8 + ((ks * 4 + l4) ^ (ra & 7))];
        const int rb = wn * 64 + i * 16 + l15;
        bfr[ks][i] = lB[rb * 8 + ((ks * 4 + l4) ^ (rb & 7))];
      }
    }
#pragma unroll
    for (int ks = 0; ks < 2; ++ks)
#pragma unroll
      for (int i = 0; i < 4; ++i)
#pragma unroll
        for (int j = 0; j < 4; ++j)
          acc[i][j] = mfma16(af[ks][i], bfr[ks][j], acc[i][j]);
    __syncthreads();
  }

  // C row m = m0 + wm*64 + i*16 + l4*4 + r ; col n = n0 + wn*64 + j*16 + l15
#pragma unroll
  for (int i = 0; i < 4; ++i) {
    const int m = m0 + wm * 64 + i * 16 + l4 * 4;
#pragma unroll
    for (int j = 0; j < 4; ++j) {
      const int n = n0 + wn * 64 + j * 16 + l15;
      if (MODE == 1) {
        const float bb = b0[n];
#pragma unroll
        for (int r = 0; r < 4; ++r)
          Of[(size_t)(m + r) * DDIM + n] = acc[i][j][r] + bb;
      } else {
        const int sel = n >> 10, nn = n & 1023;
        const int h = nn >> 6, d = nn & 63;
        const float* bp = sel == 0 ? b0 : (sel == 1 ? b1 : b2);
        const float bb = bp[nn];
        const int b = m >> 11, s = m & 2047;
        if (sel == 2) {
          union {
            bf16 h4[4];
            s16x4 v;
          } u;
#pragma unroll
          for (int r = 0; r < 4; ++r)
            u.h4[r] = __float2bfloat16(acc[i][j][r] + bb);
          *reinterpret_cast<s16x4*>(
              &O2[((size_t)(b * HH + h) * HDIM + d) * SS + s]) = u.v;
        } else {
#pragma unroll
          for (int r = 0; r < 4; ++r) {
            const float val = acc[i][j][r] + bb;
            (sel ? O1 : O0)[((size_t)(b * HH + h) * SS + (s + r)) * HDIM + d] =
                __float2bfloat16(val);
          }
        }
      }
    }
  }
}

// ---------------- fused flash attention ----------------
// grid.x = B*H*(S/64); block = 256 (4 waves), wave owns 16 q-rows.
// Bias is register-prefetched one KV-tile ahead (ping-pong bA/bB).
__global__ __launch_bounds__(256, 2) void attn_k(
    const bf16* __restrict__ Qb, const bf16* __restrict__ Kb,
    const bf16* __restrict__ Vt, const float* __restrict__ bias,
    const int* __restrict__ kpm, bf16* __restrict__ ctx) {
  __shared__ bf16x8 pl[4 * 128];  // per-wave 16x64 bf16 P scratch (swizzled)
  const int wave = threadIdx.x >> 6, lane = threadIdx.x & 63;
  const int l15 = lane & 15, l4 = lane >> 4;
  const int bid = blockIdx.x;
  const int qblk = bid & 31, bh = bid >> 5;
  const int b = bh >> 4, h = bh & 15;
  const int q0 = qblk * 64 + wave * 16;

  const bf16* Qp = Qb + ((size_t)bh * SS + q0) * HDIM;
  const bf16* Kp = Kb + (size_t)bh * SS * HDIM;
  const bf16* Vp = Vt + (size_t)bh * HDIM * SS;
  const float* Bp = bias + (size_t)h * SS * SS + (size_t)(q0 + l4 * 4) * SS;
  const int* mp = kpm + b * SS;

  bf16x8 qf[2];
#pragma unroll
  for (int ks = 0; ks < 2; ++ks)
    qf[ks] = *reinterpret_cast<const bf16x8*>(Qp + (size_t)l15 * HDIM +
                                              ks * 32 + l4 * 8);
  const f32x4 z = {0.f, 0.f, 0.f, 0.f};
  f32x4 o[4];
#pragma unroll
  for (int dd = 0; dd < 4; ++dd) o[dd] = z;
  float mrow[4], lrow[4];
#pragma unroll
  for (int r = 0; r < 4; ++r) {
    mrow[r] = -1e30f;
    lrow[r] = 0.f;
  }
  bf16* plb = reinterpret_cast<bf16*>(pl);

  float bA[16], bB[16];
  // prologue: bias tile for kb=0
#pragma unroll
  for (int jj = 0; jj < 4; ++jj)
#pragma unroll
    for (int r = 0; r < 4; ++r)
      bA[jj * 4 + r] = Bp[(size_t)r * SS + jj * 16 + l15];

  auto step = [&](int kb, const float* bc, float* bn) {
    // 1) issue next bias tile loads FIRST (wrap keeps addr in-bounds; last
    //    prefetch is discarded)
    const int kbn = (kb + 64) & (SS - 1);
#pragma unroll
    for (int jj = 0; jj < 4; ++jj)
#pragma unroll
      for (int r = 0; r < 4; ++r)
        bn[jj * 4 + r] = Bp[(size_t)r * SS + kbn + jj * 16 + l15];

    // 2) QK^T
    f32x4 sc[4];
#pragma unroll
    for (int jj = 0; jj < 4; ++jj) {
      f32x4 s = z;
#pragma unroll
      for (int ks = 0; ks < 2; ++ks) {
        bf16x8 kf = *reinterpret_cast<const bf16x8*>(
            Kp + (size_t)(kb + jj * 16 + l15) * HDIM + ks * 32 + l4 * 8);
        s = mfma16(qf[ks], kf, s);
      }
      sc[jj] = s;
    }
    // 3) scale + bias + mask + row max
    float bm[4];
#pragma unroll
    for (int r = 0; r < 4; ++r) bm[r] = -1e30f;
#pragma unroll
    for (int jj = 0; jj < 4; ++jj) {
      const int kc = kb + jj * 16 + l15;
      const bool msk = mp[kc] != 0;
#pragma unroll
      for (int r = 0; r < 4; ++r) {
        float v = msk ? -1e30f : (sc[jj][r] * 0.125f + bc[jj * 4 + r]);
        sc[jj][r] = v;
        bm[r] = fmaxf(bm[r], v);
      }
    }
#pragma unroll
    for (int off = 8; off; off >>= 1)
#pragma unroll
      for (int r = 0; r < 4; ++r) bm[r] = fmaxf(bm[r], __shfl_xor(bm[r], off));
    float alpha[4];
#pragma unroll
    for (int r = 0; r < 4; ++r) {
      const float mn = fmaxf(mrow[r], bm[r]);
      alpha[r] = __expf(mrow[r] - mn);
      mrow[r] = mn;
    }
    // 4) P = exp(S-m), row-sum, pack to LDS (swizzled) for PV A-operand
    float ps[4] = {0.f, 0.f, 0.f, 0.f};
#pragma unroll
    for (int jj = 0; jj < 4; ++jj) {
      const int col = jj * 16 + l15;
      const int ch = col >> 3, cb = col & 7;
#pragma unroll
      for (int r = 0; r < 4; ++r) {
        const float p = __expf(sc[jj][r] - mrow[r]);
        ps[r] += p;
        const int q = l4 * 4 + r;
        const int byte = wave * 2048 + q * 128 + ((ch ^ (q & 7)) * 16) + cb * 2;
        plb[byte >> 1] = __float2bfloat16(p);
      }
    }
#pragma unroll
    for (int off = 8; off; off >>= 1)
#pragma unroll
      for (int r = 0; r < 4; ++r) ps[r] += __shfl_xor(ps[r], off);
#pragma unroll
    for (int r = 0; r < 4; ++r) lrow[r] = lrow[r] * alpha[r] + ps[r];

    asm volatile("s_waitcnt lgkmcnt(0)" ::: "memory");
    bf16x8 pf[2];
#pragma unroll
    for (int ks = 0; ks < 2; ++ks)
      pf[ks] = pl[wave * 128 + l15 * 8 + ((ks * 4 + l4) ^ (l15 & 7))];
    // 5) PV
#pragma unroll
    for (int dd = 0; dd < 4; ++dd) {
#pragma unroll
      for (int r = 0; r < 4; ++r) o[dd][r] *= alpha[r];
#pragma unroll
      for (int ks = 0; ks < 2; ++ks) {
        bf16x8 vf = *reinterpret_cast<const bf16x8*>(
            Vp + (size_t)(dd * 16 + l15) * SS + kb + ks * 32 + l4 * 8);
        o[dd] = mfma16(pf[ks], vf, o[dd]);
      }
    }
  };

  for (int kb2 = 0; kb2 < SS; kb2 += 128) {
    step(kb2, bA, bB);
    step(kb2 + 64, bB, bA);
  }

  float rl[4];
#pragma unroll
  for (int r = 0; r < 4; ++r) rl[r] = 1.0f / lrow[r];
#pragma unroll
  for (int dd = 0; dd < 4; ++dd) {
#pragma unroll
    for (int r = 0; r < 4; ++r) {
      const float val = o[dd][r] * rl[r];
      const int s = q0 + l4 * 4 + r;
      ctx[((size_t)b * SS + s) * DDIM + h * HDIM + dd * 16 + l15] =
          __float2bfloat16(val);
    }
  }
}

extern "C" void kernel_launch(void* const* d_in, const int* in_sizes, int n_in,
                              void* d_out, int out_size, void* d_ws,
                              size_t ws_size, hipStream_t stream) {
  const float* x = (const float*)d_in[0];
  const float* abias = (const float*)d_in[1];
  const int* kpm = (const int*)d_in[2];
  const float* Wq = (const float*)d_in[3];
  const float* bq = (const float*)d_in[4];
  const float* Wk = (const float*)d_in[5];
  const float* bk = (const float*)d_in[6];
  const float* Wv = (const float*)d_in[7];
  const float* bv = (const float*)d_in[8];
  const float* Wo = (const float*)d_in[9];
  const float* bo = (const float*)d_in[10];
  float* out = (float*)d_out;

  char* ws = (char*)d_ws;
  bf16* xb = (bf16*)ws;                        // (B,S,D) bf16      8 MB
  bf16* Wt = (bf16*)(ws + 8388608);            // 3072x1024 bf16    6 MB
  bf16* Wot = (bf16*)(ws + 14680064);          // 1024x1024 bf16    2 MB
  bf16* Qb = (bf16*)(ws + 16777216);           // (B,H,S,HD)        8 MB
  bf16* Kb = (bf16*)(ws + 25165824);           // (B,H,S,HD)        8 MB
  bf16* Vtb = (bf16*)(ws + 33554432);          // (B,H,HD,S)        8 MB
  bf16* ctx = (bf16*)(ws + 41943040);          // (B,S,D) bf16      8 MB

  dim3 t256(256);
  cvt_k<<<dim3(2048), t256, 0, stream>>>(x, xb);
  transpose_cvt_k<<<dim3(16, 16), t256, 0, stream>>>(Wq, Wt);
  transpose_cvt_k<<<dim3(16, 16), t256, 0, stream>>>(Wk, Wt + 1024 * 1024);
  transpose_cvt_k<<<dim3(16, 16), t256, 0, stream>>>(Wv, Wt + 2 * 1024 * 1024);
  transpose_cvt_k<<<dim3(16, 16), t256, 0, stream>>>(Wo, Wot);

  gemm_bt<0><<<dim3(32, 24), t256, 0, stream>>>(xb, Wt, bq, bk, bv, Qb, Kb,
                                                Vtb, nullptr);
  attn_k<<<dim3(1024), t256, 0, stream>>>(Qb, Kb, Vtb, abias, kpm, ctx);
  gemm_bt<1><<<dim3(32, 8), t256, 0, stream>>>(ctx, Wot, bo, nullptr, nullptr,
                                               nullptr, nullptr, nullptr, out);
}

// Round 5
// 426.341 us; speedup vs baseline: 1.0681x; 1.0414x over previous
//
#include <hip/hip_runtime.h>
#include <hip/hip_bf16.h>
#include <stdint.h>

#define BB 2
#define SS 2048
#define DDIM 1024
#define HH 16
#define HDIM 64

typedef __hip_bfloat16 bf16;
typedef __bf16 bf16x8 __attribute__((ext_vector_type(8)));
typedef float f32x4 __attribute__((ext_vector_type(4)));
typedef short short8 __attribute__((ext_vector_type(8)));
typedef short s16x4 __attribute__((ext_vector_type(4)));

static __device__ __forceinline__ f32x4 mfma16(bf16x8 a, bf16x8 b, f32x4 c) {
  return __builtin_amdgcn_mfma_f32_16x16x32_bf16(a, b, c, 0, 0, 0);
}

static __device__ __forceinline__ void gload_lds16(const void* g, void* l) {
  __builtin_amdgcn_global_load_lds(
      (const __attribute__((address_space(1))) void*)g,
      (__attribute__((address_space(3))) void*)l, 16, 0, 0);
}

// ---------------- f32 -> bf16 flat convert (8 elems/thread) ----------------
__global__ __launch_bounds__(256) void cvt_k(const float* __restrict__ src,
                                             bf16* __restrict__ dst) {
  const int base = (blockIdx.x * 256 + threadIdx.x) * 8;
  float4 a = *reinterpret_cast<const float4*>(src + base);
  float4 b = *reinterpret_cast<const float4*>(src + base + 4);
  union {
    bf16 h[8];
    short8 v;
  } u;
  u.h[0] = __float2bfloat16(a.x);
  u.h[1] = __float2bfloat16(a.y);
  u.h[2] = __float2bfloat16(a.z);
  u.h[3] = __float2bfloat16(a.w);
  u.h[4] = __float2bfloat16(b.x);
  u.h[5] = __float2bfloat16(b.y);
  u.h[6] = __float2bfloat16(b.z);
  u.h[7] = __float2bfloat16(b.w);
  *reinterpret_cast<short8*>(dst + base) = u.v;
}

// ------------- transpose+convert: dst[n][k] = (bf16)src[k][n], 1024x1024 ----
__global__ __launch_bounds__(256) void transpose_cvt_k(
    const float* __restrict__ src, bf16* __restrict__ dst) {
  __shared__ float tile[64][65];
  const int t = threadIdx.x;
  const int r = t >> 2, c0 = (t & 3) * 16;
  const int bx = blockIdx.x * 64, by = blockIdx.y * 64;
  const float* sp = src + (size_t)(by + r) * DDIM + bx + c0;
#pragma unroll
  for (int j = 0; j < 16; ++j) tile[r][c0 + j] = sp[j];
  __syncthreads();
  bf16* dp = dst + (size_t)(bx + r) * DDIM + by + c0;
#pragma unroll
  for (int j = 0; j < 16; ++j) dp[j] = __float2bfloat16(tile[c0 + j][r]);
}

// ---------------- GEMM: C[m][n] = A[m][:] . Bt[n][:]  (row-major, K=1024)
// MODE 0: N=3072, scatter bf16 to Q / K / Vt with per-section f32 bias
// MODE 1: N=1024, write f32 Of[m*1024+n] + bias b0
template <int MODE>
__global__ __launch_bounds__(256, 2) void gemm_bt(
    const bf16* __restrict__ A, const bf16* __restrict__ Bt,
    const float* __restrict__ b0, const float* __restrict__ b1,
    const float* __restrict__ b2, bf16* __restrict__ O0,
    bf16* __restrict__ O1, bf16* __restrict__ O2, float* __restrict__ Of) {
  constexpr int Kd = DDIM;
  __shared__ bf16x8 lA[128 * 8];
  __shared__ bf16x8 lB[128 * 8];
  const int tid = threadIdx.x;
  const int wave = tid >> 6, lane = tid & 63;
  const int l15 = lane & 15, l4 = lane >> 4;
  const int wm = wave >> 1, wn = wave & 1;
  const int m0 = blockIdx.x * 128, n0 = blockIdx.y * 128;
  const f32x4 z = {0.f, 0.f, 0.f, 0.f};
  f32x4 acc[4][4];
#pragma unroll
  for (int i = 0; i < 4; ++i)
#pragma unroll
    for (int j = 0; j < 4; ++j) acc[i][j] = z;

  for (int k0 = 0; k0 < Kd; k0 += 64) {
#pragma unroll
    for (int j = 0; j < 4; ++j) {
      const int slot = j * 256 + tid;
      const int r = slot >> 3, cs = slot & 7;
      const int c = cs ^ (r & 7);  // pre-swizzled global source, linear LDS dest
      gload_lds16(A + (size_t)(m0 + r) * Kd + k0 + c * 8,
                  &lA[j * 256 + wave * 64]);
      gload_lds16(Bt + (size_t)(n0 + r) * Kd + k0 + c * 8,
                  &lB[j * 256 + wave * 64]);
    }
    __syncthreads();
    bf16x8 af[2][4], bfr[2][4];
#pragma unroll
    for (int ks = 0; ks < 2; ++ks) {
#pragma unroll
      for (int i = 0; i < 4; ++i) {
        const int ra = wm * 64 + i * 16 + l15;
        af[ks][i] = lA[ra * 8 + ((ks * 4 + l4) ^ (ra & 7))];
        const int rb = wn * 64 + i * 16 + l15;
        bfr[ks][i] = lB[rb * 8 + ((ks * 4 + l4) ^ (rb & 7))];
      }
    }
#pragma unroll
    for (int ks = 0; ks < 2; ++ks)
#pragma unroll
      for (int i = 0; i < 4; ++i)
#pragma unroll
        for (int j = 0; j < 4; ++j)
          acc[i][j] = mfma16(af[ks][i], bfr[ks][j], acc[i][j]);
    __syncthreads();
  }

  // C row m = m0 + wm*64 + i*16 + l4*4 + r ; col n = n0 + wn*64 + j*16 + l15
#pragma unroll
  for (int i = 0; i < 4; ++i) {
    const int m = m0 + wm * 64 + i * 16 + l4 * 4;
#pragma unroll
    for (int j = 0; j < 4; ++j) {
      const int n = n0 + wn * 64 + j * 16 + l15;
      if (MODE == 1) {
        const float bb = b0[n];
#pragma unroll
        for (int r = 0; r < 4; ++r)
          Of[(size_t)(m + r) * DDIM + n] = acc[i][j][r] + bb;
      } else {
        const int sel = n >> 10, nn = n & 1023;
        const int h = nn >> 6, d = nn & 63;
        const float* bp = sel == 0 ? b0 : (sel == 1 ? b1 : b2);
        const float bb = bp[nn];
        const int b = m >> 11, s = m & 2047;
        if (sel == 2) {
          union {
            bf16 h4[4];
            s16x4 v;
          } u;
#pragma unroll
          for (int r = 0; r < 4; ++r)
            u.h4[r] = __float2bfloat16(acc[i][j][r] + bb);
          *reinterpret_cast<s16x4*>(
              &O2[((size_t)(b * HH + h) * HDIM + d) * SS + s]) = u.v;
        } else {
#pragma unroll
          for (int r = 0; r < 4; ++r) {
            const float val = acc[i][j][r] + bb;
            (sel ? O1 : O0)[((size_t)(b * HH + h) * SS + (s + r)) * HDIM + d] =
                __float2bfloat16(val);
          }
        }
      }
    }
  }
}

// ---------------- fused flash attention ----------------
// grid.x = B*H*(S/64); block = 256 (4 waves), wave owns 16 q-rows.
// Bias tile (64x64 f32, 16KB) double-buffered in LDS via global_load_lds,
// staged one KV-step ahead; mask staged to LDS once. One barrier per step.
__global__ __launch_bounds__(256, 2) void attn_k(
    const bf16* __restrict__ Qb, const bf16* __restrict__ Kb,
    const bf16* __restrict__ Vt, const float* __restrict__ bias,
    const int* __restrict__ kpm, bf16* __restrict__ ctx) {
  __shared__ bf16x8 pl[4 * 128];     // per-wave 16x64 bf16 P scratch   8KB
  __shared__ float biasT[2 * 4096];  // 2 x 64x64 f32 bias tiles       32KB
  __shared__ int maskT[2048];        // key padding mask                8KB
  const int wave = threadIdx.x >> 6, lane = threadIdx.x & 63;
  const int l15 = lane & 15, l4 = lane >> 4;
  const int bid = blockIdx.x;
  const int qblk = bid & 31, bh = bid >> 5;
  const int b = bh >> 4, h = bh & 15;
  const int q0b = qblk * 64;
  const int q0 = q0b + wave * 16;

  const bf16* Qp = Qb + ((size_t)bh * SS + q0) * HDIM;
  const bf16* Kp = Kb + (size_t)bh * SS * HDIM;
  const bf16* Vp = Vt + (size_t)bh * HDIM * SS;
  const float* Bbase = bias + (size_t)h * SS * SS + (size_t)q0b * SS;
  const int* mp = kpm + b * SS;

  // stage mask once: 8 chunks of 1KB (wave w: chunks 2w, 2w+1)
#pragma unroll
  for (int i = 0; i < 2; ++i) {
    const int c = wave * 2 + i;
    gload_lds16(mp + c * 256 + lane * 4, &maskT[c * 256]);
  }
  // stage bias tile 0: 16 chunks of 1KB (wave w: chunks 4w..4w+3)
#pragma unroll
  for (int i = 0; i < 4; ++i) {
    const int c = wave * 4 + i;
    gload_lds16(Bbase + (size_t)(c * 4 + l4) * SS + l15 * 4, &biasT[c * 256]);
  }

  bf16x8 qf[2];
#pragma unroll
  for (int ks = 0; ks < 2; ++ks)
    qf[ks] = *reinterpret_cast<const bf16x8*>(Qp + (size_t)l15 * HDIM +
                                              ks * 32 + l4 * 8);
  const f32x4 z = {0.f, 0.f, 0.f, 0.f};
  f32x4 o[4];
#pragma unroll
  for (int dd = 0; dd < 4; ++dd) o[dd] = z;
  float mrow[4], lrow[4];
#pragma unroll
  for (int r = 0; r < 4; ++r) {
    mrow[r] = -1e30f;
    lrow[r] = 0.f;
  }
  bf16* plb = reinterpret_cast<bf16*>(pl);

  __syncthreads();  // tile0 + mask staged

  for (int t = 0; t < 32; ++t) {
    const int kb = t * 64;
    const int cur = (t & 1) * 4096, nxt = 4096 - cur;
    // 1) issue next bias tile stage (completes at this step's barrier)
    if (t < 31) {
#pragma unroll
      for (int i = 0; i < 4; ++i) {
        const int c = wave * 4 + i;
        gload_lds16(Bbase + (size_t)(c * 4 + l4) * SS + (kb + 64) + l15 * 4,
                    &biasT[nxt + c * 256]);
      }
    }
    // 2) QK^T
    f32x4 sc[4];
#pragma unroll
    for (int jj = 0; jj < 4; ++jj) {
      f32x4 s = z;
#pragma unroll
      for (int ks = 0; ks < 2; ++ks) {
        bf16x8 kf = *reinterpret_cast<const bf16x8*>(
            Kp + (size_t)(kb + jj * 16 + l15) * HDIM + ks * 32 + l4 * 8);
        s = mfma16(qf[ks], kf, s);
      }
      sc[jj] = s;
    }
    // 3) scale + bias (LDS) + mask (LDS) + row max
    float bm[4];
#pragma unroll
    for (int r = 0; r < 4; ++r) bm[r] = -1e30f;
#pragma unroll
    for (int jj = 0; jj < 4; ++jj) {
      const int kc = jj * 16 + l15;
      const bool msk = maskT[kb + kc] != 0;
#pragma unroll
      for (int r = 0; r < 4; ++r) {
        const float bvv = biasT[cur + (wave * 16 + l4 * 4 + r) * 64 + kc];
        float v = msk ? -1e30f : (sc[jj][r] * 0.125f + bvv);
        sc[jj][r] = v;
        bm[r] = fmaxf(bm[r], v);
      }
    }
#pragma unroll
    for (int off = 8; off; off >>= 1)
#pragma unroll
      for (int r = 0; r < 4; ++r) bm[r] = fmaxf(bm[r], __shfl_xor(bm[r], off));
    float alpha[4];
#pragma unroll
    for (int r = 0; r < 4; ++r) {
      const float mn = fmaxf(mrow[r], bm[r]);
      alpha[r] = __expf(mrow[r] - mn);
      mrow[r] = mn;
    }
    // 4) P = exp(S-m), row-sum, pack to LDS (swizzled) for PV A-operand
    float ps[4] = {0.f, 0.f, 0.f, 0.f};
#pragma unroll
    for (int jj = 0; jj < 4; ++jj) {
      const int col = jj * 16 + l15;
      const int ch = col >> 3, cb = col & 7;
#pragma unroll
      for (int r = 0; r < 4; ++r) {
        const float p = __expf(sc[jj][r] - mrow[r]);
        ps[r] += p;
        const int q = l4 * 4 + r;
        const int byte = wave * 2048 + q * 128 + ((ch ^ (q & 7)) * 16) + cb * 2;
        plb[byte >> 1] = __float2bfloat16(p);
      }
    }
#pragma unroll
    for (int off = 8; off; off >>= 1)
#pragma unroll
      for (int r = 0; r < 4; ++r) ps[r] += __shfl_xor(ps[r], off);
#pragma unroll
    for (int r = 0; r < 4; ++r) lrow[r] = lrow[r] * alpha[r] + ps[r];

    asm volatile("s_waitcnt lgkmcnt(0)" ::: "memory");
    bf16x8 pf[2];
#pragma unroll
    for (int ks = 0; ks < 2; ++ks)
      pf[ks] = pl[wave * 128 + l15 * 8 + ((ks * 4 + l4) ^ (l15 & 7))];
    // 5) PV
#pragma unroll
    for (int dd = 0; dd < 4; ++dd) {
#pragma unroll
      for (int r = 0; r < 4; ++r) o[dd][r] *= alpha[r];
#pragma unroll
      for (int ks = 0; ks < 2; ++ks) {
        bf16x8 vf = *reinterpret_cast<const bf16x8*>(
            Vp + (size_t)(dd * 16 + l15) * SS + kb + ks * 32 + l4 * 8);
        o[dd] = mfma16(pf[ks], vf, o[dd]);
      }
    }
    __syncthreads();  // drains stage loads; swaps buffers
  }

  float rl[4];
#pragma unroll
  for (int r = 0; r < 4; ++r) rl[r] = 1.0f / lrow[r];
#pragma unroll
  for (int dd = 0; dd < 4; ++dd) {
#pragma unroll
    for (int r = 0; r < 4; ++r) {
      const float val = o[dd][r] * rl[r];
      const int s = q0 + l4 * 4 + r;
      ctx[((size_t)b * SS + s) * DDIM + h * HDIM + dd * 16 + l15] =
          __float2bfloat16(val);
    }
  }
}

extern "C" void kernel_launch(void* const* d_in, const int* in_sizes, int n_in,
                              void* d_out, int out_size, void* d_ws,
                              size_t ws_size, hipStream_t stream) {
  const float* x = (const float*)d_in[0];
  const float* abias = (const float*)d_in[1];
  const int* kpm = (const int*)d_in[2];
  const float* Wq = (const float*)d_in[3];
  const float* bq = (const float*)d_in[4];
  const float* Wk = (const float*)d_in[5];
  const float* bk = (const float*)d_in[6];
  const float* Wv = (const float*)d_in[7];
  const float* bv = (const float*)d_in[8];
  const float* Wo = (const float*)d_in[9];
  const float* bo = (const float*)d_in[10];
  float* out = (float*)d_out;

  char* ws = (char*)d_ws;
  bf16* xb = (bf16*)ws;                        // (B,S,D) bf16      8 MB
  bf16* Wt = (bf16*)(ws + 8388608);            // 3072x1024 bf16    6 MB
  bf16* Wot = (bf16*)(ws + 14680064);          // 1024x1024 bf16    2 MB
  bf16* Qb = (bf16*)(ws + 16777216);           // (B,H,S,HD)        8 MB
  bf16* Kb = (bf16*)(ws + 25165824);           // (B,H,S,HD)        8 MB
  bf16* Vtb = (bf16*)(ws + 33554432);          // (B,H,HD,S)        8 MB
  bf16* ctx = (bf16*)(ws + 41943040);          // (B,S,D) bf16      8 MB

  dim3 t256(256);
  cvt_k<<<dim3(2048), t256, 0, stream>>>(x, xb);
  transpose_cvt_k<<<dim3(16, 16), t256, 0, stream>>>(Wq, Wt);
  transpose_cvt_k<<<dim3(16, 16), t256, 0, stream>>>(Wk, Wt + 1024 * 1024);
  transpose_cvt_k<<<dim3(16, 16), t256, 0, stream>>>(Wv, Wt + 2 * 1024 * 1024);
  transpose_cvt_k<<<dim3(16, 16), t256, 0, stream>>>(Wo, Wot);

  gemm_bt<0><<<dim3(32, 24), t256, 0, stream>>>(xb, Wt, bq, bk, bv, Qb, Kb,
                                                Vtb, nullptr);
  attn_k<<<dim3(1024), t256, 0, stream>>>(Qb, Kb, Vtb, abias, kpm, ctx);
  gemm_bt<1><<<dim3(32, 8), t256, 0, stream>>>(ctx, Wot, bo, nullptr, nullptr,
                                               nullptr, nullptr, nullptr, out);
}

// Round 7
// 395.410 us; speedup vs baseline: 1.1516x; 1.0782x over previous
//
#include <hip/hip_runtime.h>
#include <hip/hip_bf16.h>
#include <stdint.h>

#define BB 2
#define SS 2048
#define DDIM 1024
#define HH 16
#define HDIM 64

typedef __hip_bfloat16 bf16;
typedef __bf16 bf16x8 __attribute__((ext_vector_type(8)));
typedef float f32x4 __attribute__((ext_vector_type(4)));
typedef short short8 __attribute__((ext_vector_type(8)));
typedef short s16x4 __attribute__((ext_vector_type(4)));

static __device__ __forceinline__ f32x4 mfma16(bf16x8 a, bf16x8 b, f32x4 c) {
  return __builtin_amdgcn_mfma_f32_16x16x32_bf16(a, b, c, 0, 0, 0);
}

static __device__ __forceinline__ void gload_lds16(const void* g, void* l) {
  __builtin_amdgcn_global_load_lds(
      (const __attribute__((address_space(1))) void*)g,
      (__attribute__((address_space(3))) void*)l, 16, 0, 0);
}

// ---------------- f32 -> bf16 flat convert (8 elems/thread) ----------------
__global__ __launch_bounds__(256) void cvt_k(const float* __restrict__ src,
                                             bf16* __restrict__ dst) {
  const int base = (blockIdx.x * 256 + threadIdx.x) * 8;
  float4 a = *reinterpret_cast<const float4*>(src + base);
  float4 b = *reinterpret_cast<const float4*>(src + base + 4);
  union {
    bf16 h[8];
    short8 v;
  } u;
  u.h[0] = __float2bfloat16(a.x);
  u.h[1] = __float2bfloat16(a.y);
  u.h[2] = __float2bfloat16(a.z);
  u.h[3] = __float2bfloat16(a.w);
  u.h[4] = __float2bfloat16(b.x);
  u.h[5] = __float2bfloat16(b.y);
  u.h[6] = __float2bfloat16(b.z);
  u.h[7] = __float2bfloat16(b.w);
  *reinterpret_cast<short8*>(dst + base) = u.v;
}

// ------------- transpose+convert: dst[n][k] = (bf16)src[k][n], 1024x1024 ----
__global__ __launch_bounds__(256) void transpose_cvt_k(
    const float* __restrict__ src, bf16* __restrict__ dst) {
  __shared__ float tile[64][65];
  const int t = threadIdx.x;
  const int r = t >> 2, c0 = (t & 3) * 16;
  const int bx = blockIdx.x * 64, by = blockIdx.y * 64;
  const float* sp = src + (size_t)(by + r) * DDIM + bx + c0;
#pragma unroll
  for (int j = 0; j < 16; ++j) tile[r][c0 + j] = sp[j];
  __syncthreads();
  bf16* dp = dst + (size_t)(bx + r) * DDIM + by + c0;
#pragma unroll
  for (int j = 0; j < 16; ++j) dp[j] = __float2bfloat16(tile[c0 + j][r]);
}

// ---------------- GEMM: C[m][n] = A[m][:] . Bt[n][:]  (row-major, K=1024)
// MODE 0: N=3072, scatter bf16 to Q / K / Vt with per-section f32 bias
// MODE 1: N=1024, write f32 Of[m*1024+n] + bias b0
template <int MODE>
__global__ __launch_bounds__(256, 2) void gemm_bt(
    const bf16* __restrict__ A, const bf16* __restrict__ Bt,
    const float* __restrict__ b0, const float* __restrict__ b1,
    const float* __restrict__ b2, bf16* __restrict__ O0,
    bf16* __restrict__ O1, bf16* __restrict__ O2, float* __restrict__ Of) {
  constexpr int Kd = DDIM;
  __shared__ bf16x8 lA[128 * 8];
  __shared__ bf16x8 lB[128 * 8];
  const int tid = threadIdx.x;
  const int wave = tid >> 6, lane = tid & 63;
  const int l15 = lane & 15, l4 = lane >> 4;
  const int wm = wave >> 1, wn = wave & 1;
  const int m0 = blockIdx.x * 128, n0 = blockIdx.y * 128;
  const f32x4 z = {0.f, 0.f, 0.f, 0.f};
  f32x4 acc[4][4];
#pragma unroll
  for (int i = 0; i < 4; ++i)
#pragma unroll
    for (int j = 0; j < 4; ++j) acc[i][j] = z;

  for (int k0 = 0; k0 < Kd; k0 += 64) {
#pragma unroll
    for (int j = 0; j < 4; ++j) {
      const int slot = j * 256 + tid;
      const int r = slot >> 3, cs = slot & 7;
      const int c = cs ^ (r & 7);  // pre-swizzled global source, linear LDS dest
      gload_lds16(A + (size_t)(m0 + r) * Kd + k0 + c * 8,
                  &lA[j * 256 + wave * 64]);
      gload_lds16(Bt + (size_t)(n0 + r) * Kd + k0 + c * 8,
                  &lB[j * 256 + wave * 64]);
    }
    __syncthreads();
    bf16x8 af[2][4], bfr[2][4];
#pragma unroll
    for (int ks = 0; ks < 2; ++ks) {
#pragma unroll
      for (int i = 0; i < 4; ++i) {
        const int ra = wm * 64 + i * 16 + l15;
        af[ks][i] = lA[ra * 8 + ((ks * 4 + l4) ^ (ra & 7))];
        const int rb = wn * 64 + i * 16 + l15;
        bfr[ks][i] = lB[rb * 8 + ((ks * 4 + l4) ^ (rb & 7))];
      }
    }
#pragma unroll
    for (int ks = 0; ks < 2; ++ks)
#pragma unroll
      for (int i = 0; i < 4; ++i)
#pragma unroll
        for (int j = 0; j < 4; ++j)
          acc[i][j] = mfma16(af[ks][i], bfr[ks][j], acc[i][j]);
    __syncthreads();
  }

  // C row m = m0 + wm*64 + i*16 + l4*4 + r ; col n = n0 + wn*64 + j*16 + l15
#pragma unroll
  for (int i = 0; i < 4; ++i) {
    const int m = m0 + wm * 64 + i * 16 + l4 * 4;
#pragma unroll
    for (int j = 0; j < 4; ++j) {
      const int n = n0 + wn * 64 + j * 16 + l15;
      if (MODE == 1) {
        const float bb = b0[n];
#pragma unroll
        for (int r = 0; r < 4; ++r)
          Of[(size_t)(m + r) * DDIM + n] = acc[i][j][r] + bb;
      } else {
        const int sel = n >> 10, nn = n & 1023;
        const int h = nn >> 6, d = nn & 63;
        const float* bp = sel == 0 ? b0 : (sel == 1 ? b1 : b2);
        const float bb = bp[nn];
        const int b = m >> 11, s = m & 2047;
        if (sel == 2) {
          union {
            bf16 h4[4];
            s16x4 v;
          } u;
#pragma unroll
          for (int r = 0; r < 4; ++r)
            u.h4[r] = __float2bfloat16(acc[i][j][r] + bb);
          *reinterpret_cast<s16x4*>(
              &O2[((size_t)(b * HH + h) * HDIM + d) * SS + s]) = u.v;
        } else {
#pragma unroll
          for (int r = 0; r < 4; ++r) {
            const float val = acc[i][j][r] + bb;
            (sel ? O1 : O0)[((size_t)(b * HH + h) * SS + (s + r)) * HDIM + d] =
                __float2bfloat16(val);
          }
        }
      }
    }
  }
}

// ---------------- fused flash attention ----------------
// grid.x = B*H*(S/64); block = 256 (4 waves), wave owns 16 q-rows.
// NO per-step barriers: every LDS region in the loop is per-wave private
// (bias rows staged by the wave that reads them; P scratch per-wave).
// Per step, per wave, in order: issue K(8), V(8), bias-stage(t+1)(4);
// vmcnt(12) -> K + bias(t) retired; vmcnt(4) -> V retired, stage(t+1)
// stays in flight across the whole step (T4 counted-vmcnt pipelining).
__global__ __launch_bounds__(256, 3) void attn_k(
    const bf16* __restrict__ Qb, const bf16* __restrict__ Kb,
    const bf16* __restrict__ Vt, const float* __restrict__ bias,
    const int* __restrict__ kpm, bf16* __restrict__ ctx) {
  __shared__ bf16x8 pl[4 * 128];     // per-wave 16x64 bf16 P scratch   8KB
  __shared__ float biasT[2 * 4096];  // 2 x 64x64 f32 bias tiles       32KB
  __shared__ int maskT[2048];        // key padding mask                8KB
  const int wave = threadIdx.x >> 6, lane = threadIdx.x & 63;
  const int l15 = lane & 15, l4 = lane >> 4;
  const int bid = blockIdx.x;
  const int qblk = bid & 31, bh = bid >> 5;
  const int b = bh >> 4, h = bh & 15;
  const int q0b = qblk * 64;
  const int q0 = q0b + wave * 16;

  const bf16* Qp = Qb + ((size_t)bh * SS + q0) * HDIM;
  const bf16* Kp = Kb + (size_t)bh * SS * HDIM;
  const bf16* Vp = Vt + (size_t)bh * HDIM * SS;
  const float* Bbase = bias + (size_t)h * SS * SS + (size_t)q0b * SS;
  const int* mp = kpm + b * SS;

  // stage mask once: 8 chunks of 1KB (wave w: chunks 2w, 2w+1)
#pragma unroll
  for (int i = 0; i < 2; ++i) {
    const int c = wave * 2 + i;
    gload_lds16(mp + c * 256 + lane * 4, &maskT[c * 256]);
  }
  // stage bias tile 0 (this wave's 16 rows: chunks 4w..4w+3)
#pragma unroll
  for (int i = 0; i < 4; ++i) {
    const int c = wave * 4 + i;
    gload_lds16(Bbase + (size_t)(c * 4 + l4) * SS + l15 * 4, &biasT[c * 256]);
  }

  bf16x8 qf[2];
#pragma unroll
  for (int ks = 0; ks < 2; ++ks)
    qf[ks] = *reinterpret_cast<const bf16x8*>(Qp + (size_t)l15 * HDIM +
                                              ks * 32 + l4 * 8);
  const f32x4 z = {0.f, 0.f, 0.f, 0.f};
  f32x4 o[4];
#pragma unroll
  for (int dd = 0; dd < 4; ++dd) o[dd] = z;
  float mrow[4], lrow[4];
#pragma unroll
  for (int r = 0; r < 4; ++r) {
    mrow[r] = -1e30f;
    lrow[r] = 0.f;
  }
  bf16* plb = reinterpret_cast<bf16*>(pl);

  asm volatile("s_waitcnt vmcnt(0)" ::: "memory");
  __syncthreads();  // mask (cross-wave) + tile0 staged; ONLY block barrier

  for (int t = 0; t < 32; ++t) {
    const int kb = t * 64;
    const int cur = (t & 1) * 4096, nxt = 4096 - cur;

    // 1) issue K loads (8)
    bf16x8 kf[4][2];
#pragma unroll
    for (int jj = 0; jj < 4; ++jj)
#pragma unroll
      for (int ks = 0; ks < 2; ++ks)
        kf[jj][ks] = *reinterpret_cast<const bf16x8*>(
            Kp + (size_t)(kb + jj * 16 + l15) * HDIM + ks * 32 + l4 * 8);
    // 2) issue V loads (8)
    bf16x8 vf[4][2];
#pragma unroll
    for (int dd = 0; dd < 4; ++dd)
#pragma unroll
      for (int ks = 0; ks < 2; ++ks)
        vf[dd][ks] = *reinterpret_cast<const bf16x8*>(
            Vp + (size_t)(dd * 16 + l15) * SS + kb + ks * 32 + l4 * 8);
    // 3) issue bias stage for t+1 (4; wrap keeps addr in-bounds, extra
    //    prefetch at t=31 is discarded)
    const int kbn = (kb + 64) & (SS - 1);
#pragma unroll
    for (int i = 0; i < 4; ++i) {
      const int c = wave * 4 + i;
      gload_lds16(Bbase + (size_t)(c * 4 + l4) * SS + kbn + l15 * 4,
                  &biasT[nxt + c * 256]);
    }
    // K + bias(t) retired; V(8) + stage(t+1)(4) still outstanding
    asm volatile("s_waitcnt vmcnt(12)" ::: "memory");
    __builtin_amdgcn_sched_barrier(0);

    // 4) QK^T
    f32x4 sc[4];
#pragma unroll
    for (int jj = 0; jj < 4; ++jj) {
      f32x4 s = z;
#pragma unroll
      for (int ks = 0; ks < 2; ++ks) s = mfma16(qf[ks], kf[jj][ks], s);
      sc[jj] = s;
    }
    // 5) scale + bias (LDS, own rows) + mask (LDS) + row max
    float bm[4];
#pragma unroll
    for (int r = 0; r < 4; ++r) bm[r] = -1e30f;
#pragma unroll
    for (int jj = 0; jj < 4; ++jj) {
      const int kc = jj * 16 + l15;
      const bool msk = maskT[kb + kc] != 0;
#pragma unroll
      for (int r = 0; r < 4; ++r) {
        const float bvv = biasT[cur + (wave * 16 + l4 * 4 + r) * 64 + kc];
        float v = msk ? -1e30f : (sc[jj][r] * 0.125f + bvv);
        sc[jj][r] = v;
        bm[r] = fmaxf(bm[r], v);
      }
    }
#pragma unroll
    for (int off = 8; off; off >>= 1)
#pragma unroll
      for (int r = 0; r < 4; ++r) bm[r] = fmaxf(bm[r], __shfl_xor(bm[r], off));
    float alpha[4];
#pragma unroll
    for (int r = 0; r < 4; ++r) {
      const float mn = fmaxf(mrow[r], bm[r]);
      alpha[r] = __expf(mrow[r] - mn);
      mrow[r] = mn;
    }
    // 6) P = exp(S-m), row-sum, pack to per-wave LDS (swizzled)
    float ps[4] = {0.f, 0.f, 0.f, 0.f};
#pragma unroll
    for (int jj = 0; jj < 4; ++jj) {
      const int col = jj * 16 + l15;
      const int ch = col >> 3, cb = col & 7;
#pragma unroll
      for (int r = 0; r < 4; ++r) {
        const float p = __expf(sc[jj][r] - mrow[r]);
        ps[r] += p;
        const int q = l4 * 4 + r;
        const int byte = wave * 2048 + q * 128 + ((ch ^ (q & 7)) * 16) + cb * 2;
        plb[byte >> 1] = __float2bfloat16(p);
      }
    }
#pragma unroll
    for (int off = 8; off; off >>= 1)
#pragma unroll
      for (int r = 0; r < 4; ++r) ps[r] += __shfl_xor(ps[r], off);
#pragma unroll
    for (int r = 0; r < 4; ++r) lrow[r] = lrow[r] * alpha[r] + ps[r];

    asm volatile("s_waitcnt lgkmcnt(0)" ::: "memory");
    __builtin_amdgcn_sched_barrier(0);
    bf16x8 pf[2];
#pragma unroll
    for (int ks = 0; ks < 2; ++ks)
      pf[ks] = pl[wave * 128 + l15 * 8 + ((ks * 4 + l4) ^ (l15 & 7))];

    // V retired; only stage(t+1) (4) outstanding into next step
    asm volatile("s_waitcnt vmcnt(4)" ::: "memory");
    __builtin_amdgcn_sched_barrier(0);
    // 7) PV
#pragma unroll
    for (int dd = 0; dd < 4; ++dd) {
#pragma unroll
      for (int r = 0; r < 4; ++r) o[dd][r] *= alpha[r];
#pragma unroll
      for (int ks = 0; ks < 2; ++ks) o[dd] = mfma16(pf[ks], vf[dd][ks], o[dd]);
    }
  }

  float rl[4];
#pragma unroll
  for (int r = 0; r < 4; ++r) rl[r] = 1.0f / lrow[r];
#pragma unroll
  for (int dd = 0; dd < 4; ++dd) {
#pragma unroll
    for (int r = 0; r < 4; ++r) {
      const float val = o[dd][r] * rl[r];
      const int s = q0 + l4 * 4 + r;
      ctx[((size_t)b * SS + s) * DDIM + h * HDIM + dd * 16 + l15] =
          __float2bfloat16(val);
    }
  }
}

extern "C" void kernel_launch(void* const* d_in, const int* in_sizes, int n_in,
                              void* d_out, int out_size, void* d_ws,
                              size_t ws_size, hipStream_t stream) {
  const float* x = (const float*)d_in[0];
  const float* abias = (const float*)d_in[1];
  const int* kpm = (const int*)d_in[2];
  const float* Wq = (const float*)d_in[3];
  const float* bq = (const float*)d_in[4];
  const float* Wk = (const float*)d_in[5];
  const float* bk = (const float*)d_in[6];
  const float* Wv = (const float*)d_in[7];
  const float* bv = (const float*)d_in[8];
  const float* Wo = (const float*)d_in[9];
  const float* bo = (const float*)d_in[10];
  float* out = (float*)d_out;

  char* ws = (char*)d_ws;
  bf16* xb = (bf16*)ws;                        // (B,S,D) bf16      8 MB
  bf16* Wt = (bf16*)(ws + 8388608);            // 3072x1024 bf16    6 MB
  bf16* Wot = (bf16*)(ws + 14680064);          // 1024x1024 bf16    2 MB
  bf16* Qb = (bf16*)(ws + 16777216);           // (B,H,S,HD)        8 MB
  bf16* Kb = (bf16*)(ws + 25165824);           // (B,H,S,HD)        8 MB
  bf16* Vtb = (bf16*)(ws + 33554432);          // (B,H,HD,S)        8 MB
  bf16* ctx = (bf16*)(ws + 41943040);          // (B,S,D) bf16      8 MB

  dim3 t256(256);
  cvt_k<<<dim3(2048), t256, 0, stream>>>(x, xb);
  transpose_cvt_k<<<dim3(16, 16), t256, 0, stream>>>(Wq, Wt);
  transpose_cvt_k<<<dim3(16, 16), t256, 0, stream>>>(Wk, Wt + 1024 * 1024);
  transpose_cvt_k<<<dim3(16, 16), t256, 0, stream>>>(Wv, Wt + 2 * 1024 * 1024);
  transpose_cvt_k<<<dim3(16, 16), t256, 0, stream>>>(Wo, Wot);

  gemm_bt<0><<<dim3(32, 24), t256, 0, stream>>>(xb, Wt, bq, bk, bv, Qb, Kb,
                                                Vtb, nullptr);
  attn_k<<<dim3(1024), t256, 0, stream>>>(Qb, Kb, Vtb, abias, kpm, ctx);
  gemm_bt<1><<<dim3(32, 8), t256, 0, stream>>>(ctx, Wot, bo, nullptr, nullptr,
                                               nullptr, nullptr, nullptr, out);
}

// Round 8
// 395.316 us; speedup vs baseline: 1.1519x; 1.0002x over previous
//
#include <hip/hip_runtime.h>
#include <hip/hip_bf16.h>
#include <stdint.h>

#define BB 2
#define SS 2048
#define DDIM 1024
#define HH 16
#define HDIM 64

typedef __hip_bfloat16 bf16;
typedef __bf16 bf16x8 __attribute__((ext_vector_type(8)));
typedef float f32x4 __attribute__((ext_vector_type(4)));
typedef short short8 __attribute__((ext_vector_type(8)));
typedef short s16x4 __attribute__((ext_vector_type(4)));

static __device__ __forceinline__ f32x4 mfma16(bf16x8 a, bf16x8 b, f32x4 c) {
  return __builtin_amdgcn_mfma_f32_16x16x32_bf16(a, b, c, 0, 0, 0);
}

static __device__ __forceinline__ void gload_lds16(const void* g, void* l) {
  __builtin_amdgcn_global_load_lds(
      (const __attribute__((address_space(1))) void*)g,
      (__attribute__((address_space(3))) void*)l, 16, 0, 0);
}

// ---------------- f32 -> bf16 flat convert (8 elems/thread) ----------------
__global__ __launch_bounds__(256) void cvt_k(const float* __restrict__ src,
                                             bf16* __restrict__ dst) {
  const int base = (blockIdx.x * 256 + threadIdx.x) * 8;
  float4 a = *reinterpret_cast<const float4*>(src + base);
  float4 b = *reinterpret_cast<const float4*>(src + base + 4);
  union {
    bf16 h[8];
    short8 v;
  } u;
  u.h[0] = __float2bfloat16(a.x);
  u.h[1] = __float2bfloat16(a.y);
  u.h[2] = __float2bfloat16(a.z);
  u.h[3] = __float2bfloat16(a.w);
  u.h[4] = __float2bfloat16(b.x);
  u.h[5] = __float2bfloat16(b.y);
  u.h[6] = __float2bfloat16(b.z);
  u.h[7] = __float2bfloat16(b.w);
  *reinterpret_cast<short8*>(dst + base) = u.v;
}

// ------------- transpose+convert: dst[n][k] = (bf16)src[k][n], 1024x1024 ----
__global__ __launch_bounds__(256) void transpose_cvt_k(
    const float* __restrict__ src, bf16* __restrict__ dst) {
  __shared__ float tile[64][65];
  const int t = threadIdx.x;
  const int r = t >> 2, c0 = (t & 3) * 16;
  const int bx = blockIdx.x * 64, by = blockIdx.y * 64;
  const float* sp = src + (size_t)(by + r) * DDIM + bx + c0;
#pragma unroll
  for (int j = 0; j < 16; ++j) tile[r][c0 + j] = sp[j];
  __syncthreads();
  bf16* dp = dst + (size_t)(bx + r) * DDIM + by + c0;
#pragma unroll
  for (int j = 0; j < 16; ++j) dp[j] = __float2bfloat16(tile[c0 + j][r]);
}

// ---------------- GEMM: C[m][n] = A[m][:] . Bt[n][:]  (row-major, K=1024)
// MODE 0: N=3072, scatter bf16 to Q / K / Vt with per-section f32 bias
// MODE 1: N=1024, write f32 Of[m*1024+n] + bias b0
template <int MODE>
__global__ __launch_bounds__(256, 2) void gemm_bt(
    const bf16* __restrict__ A, const bf16* __restrict__ Bt,
    const float* __restrict__ b0, const float* __restrict__ b1,
    const float* __restrict__ b2, bf16* __restrict__ O0,
    bf16* __restrict__ O1, bf16* __restrict__ O2, float* __restrict__ Of) {
  constexpr int Kd = DDIM;
  __shared__ bf16x8 lA[128 * 8];
  __shared__ bf16x8 lB[128 * 8];
  const int tid = threadIdx.x;
  const int wave = tid >> 6, lane = tid & 63;
  const int l15 = lane & 15, l4 = lane >> 4;
  const int wm = wave >> 1, wn = wave & 1;
  const int m0 = blockIdx.x * 128, n0 = blockIdx.y * 128;
  const f32x4 z = {0.f, 0.f, 0.f, 0.f};
  f32x4 acc[4][4];
#pragma unroll
  for (int i = 0; i < 4; ++i)
#pragma unroll
    for (int j = 0; j < 4; ++j) acc[i][j] = z;

  for (int k0 = 0; k0 < Kd; k0 += 64) {
#pragma unroll
    for (int j = 0; j < 4; ++j) {
      const int slot = j * 256 + tid;
      const int r = slot >> 3, cs = slot & 7;
      const int c = cs ^ (r & 7);  // pre-swizzled global source, linear LDS dest
      gload_lds16(A + (size_t)(m0 + r) * Kd + k0 + c * 8,
                  &lA[j * 256 + wave * 64]);
      gload_lds16(Bt + (size_t)(n0 + r) * Kd + k0 + c * 8,
                  &lB[j * 256 + wave * 64]);
    }
    __syncthreads();
    bf16x8 af[2][4], bfr[2][4];
#pragma unroll
    for (int ks = 0; ks < 2; ++ks) {
#pragma unroll
      for (int i = 0; i < 4; ++i) {
        const int ra = wm * 64 + i * 16 + l15;
        af[ks][i] = lA[ra * 8 + ((ks * 4 + l4) ^ (ra & 7))];
        const int rb = wn * 64 + i * 16 + l15;
        bfr[ks][i] = lB[rb * 8 + ((ks * 4 + l4) ^ (rb & 7))];
      }
    }
#pragma unroll
    for (int ks = 0; ks < 2; ++ks)
#pragma unroll
      for (int i = 0; i < 4; ++i)
#pragma unroll
        for (int j = 0; j < 4; ++j)
          acc[i][j] = mfma16(af[ks][i], bfr[ks][j], acc[i][j]);
    __syncthreads();
  }

  // C row m = m0 + wm*64 + i*16 + l4*4 + r ; col n = n0 + wn*64 + j*16 + l15
#pragma unroll
  for (int i = 0; i < 4; ++i) {
    const int m = m0 + wm * 64 + i * 16 + l4 * 4;
#pragma unroll
    for (int j = 0; j < 4; ++j) {
      const int n = n0 + wn * 64 + j * 16 + l15;
      if (MODE == 1) {
        const float bb = b0[n];
#pragma unroll
        for (int r = 0; r < 4; ++r)
          Of[(size_t)(m + r) * DDIM + n] = acc[i][j][r] + bb;
      } else {
        const int sel = n >> 10, nn = n & 1023;
        const int h = nn >> 6, d = nn & 63;
        const float* bp = sel == 0 ? b0 : (sel == 1 ? b1 : b2);
        const float bb = bp[nn];
        const int b = m >> 11, s = m & 2047;
        if (sel == 2) {
          union {
            bf16 h4[4];
            s16x4 v;
          } u;
#pragma unroll
          for (int r = 0; r < 4; ++r)
            u.h4[r] = __float2bfloat16(acc[i][j][r] + bb);
          *reinterpret_cast<s16x4*>(
              &O2[((size_t)(b * HH + h) * HDIM + d) * SS + s]) = u.v;
        } else {
#pragma unroll
          for (int r = 0; r < 4; ++r) {
            const float val = acc[i][j][r] + bb;
            (sel ? O1 : O0)[((size_t)(b * HH + h) * SS + (s + r)) * HDIM + d] =
                __float2bfloat16(val);
          }
        }
      }
    }
  }
}

// ---------------- fused flash attention ----------------
// grid.x = B*H*(S/64); block = 256 (4 waves), wave owns 16 q-rows.
// Full one-step-ahead pipeline, no in-loop barriers:
//   top:    vmcnt(16) -> bias stage(t) retired; read bias+mask LDS->regs
//   issue:  stage bias(t+1) [4], K(t+1) [8], V(t+1) [8]  (oldest-first: stage)
//   vmcnt(20) -> K(t)/V(t) (issued one full step ago) retired
//   compute QK^T / softmax / PV with current-register buffers.
// All LDS bias reads happen BEFORE same-step gload_lds issues, so the
// compiler's loop-carried LDS dependency wait is the same vmcnt(16).
__global__ __launch_bounds__(256, 2) void attn_k(
    const bf16* __restrict__ Qb, const bf16* __restrict__ Kb,
    const bf16* __restrict__ Vt, const float* __restrict__ bias,
    const int* __restrict__ kpm, bf16* __restrict__ ctx) {
  __shared__ bf16x8 pl[4 * 128];     // per-wave 16x64 bf16 P scratch   8KB
  __shared__ float biasT[2 * 4096];  // 2 x 64x64 f32 bias tiles       32KB
  __shared__ int maskT[2048];        // key padding mask                8KB
  const int wave = threadIdx.x >> 6, lane = threadIdx.x & 63;
  const int l15 = lane & 15, l4 = lane >> 4;
  const int bid = blockIdx.x;
  const int qblk = bid & 31, bh = bid >> 5;
  const int b = bh >> 4, h = bh & 15;
  const int q0b = qblk * 64;
  const int q0 = q0b + wave * 16;

  const bf16* Qp = Qb + ((size_t)bh * SS + q0) * HDIM;
  const bf16* Kp = Kb + (size_t)bh * SS * HDIM;
  const bf16* Vp = Vt + (size_t)bh * HDIM * SS;
  const float* Bbase = bias + (size_t)h * SS * SS + (size_t)q0b * SS;
  const int* mp = kpm + b * SS;

  // ---- prologue staging ----
  // mask: 8 chunks of 1KB (wave w: chunks 2w, 2w+1)
#pragma unroll
  for (int i = 0; i < 2; ++i) {
    const int c = wave * 2 + i;
    gload_lds16(mp + c * 256 + lane * 4, &maskT[c * 256]);
  }
  // bias tile 0 (this wave's 16 rows: chunks 4w..4w+3)
#pragma unroll
  for (int i = 0; i < 4; ++i) {
    const int c = wave * 4 + i;
    gload_lds16(Bbase + (size_t)(c * 4 + l4) * SS + l15 * 4, &biasT[c * 256]);
  }

  bf16x8 qf[2];
#pragma unroll
  for (int ks = 0; ks < 2; ++ks)
    qf[ks] = *reinterpret_cast<const bf16x8*>(Qp + (size_t)l15 * HDIM +
                                              ks * 32 + l4 * 8);
  // K/V tile 0 into register buffer A
  bf16x8 kfA[4][2], kfB[4][2], vfA[4][2], vfB[4][2];
#pragma unroll
  for (int jj = 0; jj < 4; ++jj)
#pragma unroll
    for (int ks = 0; ks < 2; ++ks)
      kfA[jj][ks] = *reinterpret_cast<const bf16x8*>(
          Kp + (size_t)(jj * 16 + l15) * HDIM + ks * 32 + l4 * 8);
#pragma unroll
  for (int dd = 0; dd < 4; ++dd)
#pragma unroll
    for (int ks = 0; ks < 2; ++ks)
      vfA[dd][ks] = *reinterpret_cast<const bf16x8*>(
          Vp + (size_t)(dd * 16 + l15) * SS + ks * 32 + l4 * 8);

  const f32x4 z = {0.f, 0.f, 0.f, 0.f};
  f32x4 o[4];
#pragma unroll
  for (int dd = 0; dd < 4; ++dd) o[dd] = z;
  float mrow[4], lrow[4];
#pragma unroll
  for (int r = 0; r < 4; ++r) {
    mrow[r] = -1e30f;
    lrow[r] = 0.f;
  }
  bf16* plb = reinterpret_cast<bf16*>(pl);

  asm volatile("s_waitcnt vmcnt(0)" ::: "memory");
  __syncthreads();  // mask + tile0 staged; ONLY block barrier

  auto step = [&](int t, bf16x8 (&kc)[4][2], bf16x8 (&vc)[4][2],
                  bf16x8 (&kn)[4][2], bf16x8 (&vn)[4][2]) {
    const int kb = t * 64;
    const int cur = (t & 1) * 4096, nxt = 4096 - cur;

    // (a) bias stage(t) retired (16 = K/V(t) still outstanding)
    asm volatile("s_waitcnt vmcnt(16)" ::: "memory");
    // bias(t) + mask -> regs (all LDS reads BEFORE new gload_lds issues)
    int mreg[4];
    float breg[4][4];
#pragma unroll
    for (int jj = 0; jj < 4; ++jj) {
      mreg[jj] = maskT[kb + jj * 16 + l15];
#pragma unroll
      for (int r = 0; r < 4; ++r)
        breg[jj][r] = biasT[cur + (wave * 16 + l4 * 4 + r) * 64 + jj * 16 + l15];
    }

    // (b) issue next-tile loads: stage FIRST (so vmcnt(16) isolates it next
    //     step), then K, then V.  Wrap keeps addresses in-bounds at t=31.
    const int kbn = (kb + 64) & (SS - 1);
#pragma unroll
    for (int i = 0; i < 4; ++i) {
      const int c = wave * 4 + i;
      gload_lds16(Bbase + (size_t)(c * 4 + l4) * SS + kbn + l15 * 4,
                  &biasT[nxt + c * 256]);
    }
#pragma unroll
    for (int jj = 0; jj < 4; ++jj)
#pragma unroll
      for (int ks = 0; ks < 2; ++ks)
        kn[jj][ks] = *reinterpret_cast<const bf16x8*>(
            Kp + (size_t)(kbn + jj * 16 + l15) * HDIM + ks * 32 + l4 * 8);
#pragma unroll
    for (int dd = 0; dd < 4; ++dd)
#pragma unroll
      for (int ks = 0; ks < 2; ++ks)
        vn[dd][ks] = *reinterpret_cast<const bf16x8*>(
            Vp + (size_t)(dd * 16 + l15) * SS + kbn + ks * 32 + l4 * 8);

    // (c) K(t)/V(t) retired; the 20 just-issued stay in flight all step
    asm volatile("s_waitcnt vmcnt(20)" ::: "memory");
    __builtin_amdgcn_sched_barrier(0);

    // (d) QK^T
    f32x4 sc[4];
#pragma unroll
    for (int jj = 0; jj < 4; ++jj) {
      f32x4 s = z;
#pragma unroll
      for (int ks = 0; ks < 2; ++ks) s = mfma16(qf[ks], kc[jj][ks], s);
      sc[jj] = s;
    }
    // scale + bias + mask + row max
    float bm[4];
#pragma unroll
    for (int r = 0; r < 4; ++r) bm[r] = -1e30f;
#pragma unroll
    for (int jj = 0; jj < 4; ++jj) {
      const bool msk = mreg[jj] != 0;
#pragma unroll
      for (int r = 0; r < 4; ++r) {
        float v = msk ? -1e30f : (sc[jj][r] * 0.125f + breg[jj][r]);
        sc[jj][r] = v;
        bm[r] = fmaxf(bm[r], v);
      }
    }
#pragma unroll
    for (int off = 8; off; off >>= 1)
#pragma unroll
      for (int r = 0; r < 4; ++r) bm[r] = fmaxf(bm[r], __shfl_xor(bm[r], off));
    float alpha[4];
#pragma unroll
    for (int r = 0; r < 4; ++r) {
      const float mn = fmaxf(mrow[r], bm[r]);
      alpha[r] = __expf(mrow[r] - mn);
      mrow[r] = mn;
    }
    // P = exp(S-m), row-sum, pack to per-wave LDS (swizzled)
    float ps[4] = {0.f, 0.f, 0.f, 0.f};
#pragma unroll
    for (int jj = 0; jj < 4; ++jj) {
      const int col = jj * 16 + l15;
      const int ch = col >> 3, cb = col & 7;
#pragma unroll
      for (int r = 0; r < 4; ++r) {
        const float p = __expf(sc[jj][r] - mrow[r]);
        ps[r] += p;
        const int q = l4 * 4 + r;
        const int byte = wave * 2048 + q * 128 + ((ch ^ (q & 7)) * 16) + cb * 2;
        plb[byte >> 1] = __float2bfloat16(p);
      }
    }
#pragma unroll
    for (int off = 8; off; off >>= 1)
#pragma unroll
      for (int r = 0; r < 4; ++r) ps[r] += __shfl_xor(ps[r], off);
#pragma unroll
    for (int r = 0; r < 4; ++r) lrow[r] = lrow[r] * alpha[r] + ps[r];

    asm volatile("s_waitcnt lgkmcnt(0)" ::: "memory");
    __builtin_amdgcn_sched_barrier(0);
    bf16x8 pf[2];
#pragma unroll
    for (int ks = 0; ks < 2; ++ks)
      pf[ks] = pl[wave * 128 + l15 * 8 + ((ks * 4 + l4) ^ (l15 & 7))];
    // PV
#pragma unroll
    for (int dd = 0; dd < 4; ++dd) {
#pragma unroll
      for (int r = 0; r < 4; ++r) o[dd][r] *= alpha[r];
#pragma unroll
      for (int ks = 0; ks < 2; ++ks) o[dd] = mfma16(pf[ks], vc[dd][ks], o[dd]);
    }
  };

  for (int t2 = 0; t2 < 16; ++t2) {
    step(t2 * 2, kfA, vfA, kfB, vfB);
    step(t2 * 2 + 1, kfB, vfB, kfA, vfA);
  }

  float rl[4];
#pragma unroll
  for (int r = 0; r < 4; ++r) rl[r] = 1.0f / lrow[r];
#pragma unroll
  for (int dd = 0; dd < 4; ++dd) {
#pragma unroll
    for (int r = 0; r < 4; ++r) {
      const float val = o[dd][r] * rl[r];
      const int s = q0 + l4 * 4 + r;
      ctx[((size_t)b * SS + s) * DDIM + h * HDIM + dd * 16 + l15] =
          __float2bfloat16(val);
    }
  }
}

extern "C" void kernel_launch(void* const* d_in, const int* in_sizes, int n_in,
                              void* d_out, int out_size, void* d_ws,
                              size_t ws_size, hipStream_t stream) {
  const float* x = (const float*)d_in[0];
  const float* abias = (const float*)d_in[1];
  const int* kpm = (const int*)d_in[2];
  const float* Wq = (const float*)d_in[3];
  const float* bq = (const float*)d_in[4];
  const float* Wk = (const float*)d_in[5];
  const float* bk = (const float*)d_in[6];
  const float* Wv = (const float*)d_in[7];
  const float* bv = (const float*)d_in[8];
  const float* Wo = (const float*)d_in[9];
  const float* bo = (const float*)d_in[10];
  float* out = (float*)d_out;

  char* ws = (char*)d_ws;
  bf16* xb = (bf16*)ws;                        // (B,S,D) bf16      8 MB
  bf16* Wt = (bf16*)(ws + 8388608);            // 3072x1024 bf16    6 MB
  bf16* Wot = (bf16*)(ws + 14680064);          // 1024x1024 bf16    2 MB
  bf16* Qb = (bf16*)(ws + 16777216);           // (B,H,S,HD)        8 MB
  bf16* Kb = (bf16*)(ws + 25165824);           // (B,H,S,HD)        8 MB
  bf16* Vtb = (bf16*)(ws + 33554432);          // (B,H,HD,S)        8 MB
  bf16* ctx = (bf16*)(ws + 41943040);          // (B,S,D) bf16      8 MB

  dim3 t256(256);
  cvt_k<<<dim3(2048), t256, 0, stream>>>(x, xb);
  transpose_cvt_k<<<dim3(16, 16), t256, 0, stream>>>(Wq, Wt);
  transpose_cvt_k<<<dim3(16, 16), t256, 0, stream>>>(Wk, Wt + 1024 * 1024);
  transpose_cvt_k<<<dim3(16, 16), t256, 0, stream>>>(Wv, Wt + 2 * 1024 * 1024);
  transpose_cvt_k<<<dim3(16, 16), t256, 0, stream>>>(Wo, Wot);

  gemm_bt<0><<<dim3(32, 24), t256, 0, stream>>>(xb, Wt, bq, bk, bv, Qb, Kb,
                                                Vtb, nullptr);
  attn_k<<<dim3(1024), t256, 0, stream>>>(Qb, Kb, Vtb, abias, kpm, ctx);
  gemm_bt<1><<<dim3(32, 8), t256, 0, stream>>>(ctx, Wot, bo, nullptr, nullptr,
                                               nullptr, nullptr, nullptr, out);
}

// Round 9
// 393.247 us; speedup vs baseline: 1.1579x; 1.0053x over previous
//
#include <hip/hip_runtime.h>
#include <hip/hip_bf16.h>
#include <stdint.h>

#define BB 2
#define SS 2048
#define DDIM 1024
#define HH 16
#define HDIM 64

typedef __hip_bfloat16 bf16;
typedef __bf16 bf16x8 __attribute__((ext_vector_type(8)));
typedef float f32x4 __attribute__((ext_vector_type(4)));
typedef int i32x4 __attribute__((ext_vector_type(4)));
typedef short short8 __attribute__((ext_vector_type(8)));
typedef short s16x4 __attribute__((ext_vector_type(4)));

static __device__ __forceinline__ f32x4 mfma16(bf16x8 a, bf16x8 b, f32x4 c) {
  return __builtin_amdgcn_mfma_f32_16x16x32_bf16(a, b, c, 0, 0, 0);
}

static __device__ __forceinline__ void gload_lds16(const void* g, void* l) {
  __builtin_amdgcn_global_load_lds(
      (const __attribute__((address_space(1))) void*)g,
      (__attribute__((address_space(3))) void*)l, 16, 0, 0);
}

// ---------------- f32 -> bf16 flat convert (8 elems/thread) ----------------
__global__ __launch_bounds__(256) void cvt_k(const float* __restrict__ src,
                                             bf16* __restrict__ dst) {
  const int base = (blockIdx.x * 256 + threadIdx.x) * 8;
  float4 a = *reinterpret_cast<const float4*>(src + base);
  float4 b = *reinterpret_cast<const float4*>(src + base + 4);
  union {
    bf16 h[8];
    short8 v;
  } u;
  u.h[0] = __float2bfloat16(a.x);
  u.h[1] = __float2bfloat16(a.y);
  u.h[2] = __float2bfloat16(a.z);
  u.h[3] = __float2bfloat16(a.w);
  u.h[4] = __float2bfloat16(b.x);
  u.h[5] = __float2bfloat16(b.y);
  u.h[6] = __float2bfloat16(b.z);
  u.h[7] = __float2bfloat16(b.w);
  *reinterpret_cast<short8*>(dst + base) = u.v;
}

// ------------- transpose+convert: dst[n][k] = (bf16)src[k][n], 1024x1024 ----
__global__ __launch_bounds__(256) void transpose_cvt_k(
    const float* __restrict__ src, bf16* __restrict__ dst) {
  __shared__ float tile[64][65];
  const int t = threadIdx.x;
  const int r = t >> 2, c0 = (t & 3) * 16;
  const int bx = blockIdx.x * 64, by = blockIdx.y * 64;
  const float* sp = src + (size_t)(by + r) * DDIM + bx + c0;
#pragma unroll
  for (int j = 0; j < 16; ++j) tile[r][c0 + j] = sp[j];
  __syncthreads();
  bf16* dp = dst + (size_t)(bx + r) * DDIM + by + c0;
#pragma unroll
  for (int j = 0; j < 16; ++j) dp[j] = __float2bfloat16(tile[c0 + j][r]);
}

// ---------------- GEMM: C[m][n] = A[m][:] . Bt[n][:]  (row-major, K=1024)
// MODE 0: N=3072, scatter bf16 to Q / K / Vt with per-section f32 bias
// MODE 1: N=1024, write f32 Of[m*1024+n] + bias b0
template <int MODE>
__global__ __launch_bounds__(256, 2) void gemm_bt(
    const bf16* __restrict__ A, const bf16* __restrict__ Bt,
    const float* __restrict__ b0, const float* __restrict__ b1,
    const float* __restrict__ b2, bf16* __restrict__ O0,
    bf16* __restrict__ O1, bf16* __restrict__ O2, float* __restrict__ Of) {
  constexpr int Kd = DDIM;
  __shared__ bf16x8 lA[128 * 8];
  __shared__ bf16x8 lB[128 * 8];
  const int tid = threadIdx.x;
  const int wave = tid >> 6, lane = tid & 63;
  const int l15 = lane & 15, l4 = lane >> 4;
  const int wm = wave >> 1, wn = wave & 1;
  const int m0 = blockIdx.x * 128, n0 = blockIdx.y * 128;
  const f32x4 z = {0.f, 0.f, 0.f, 0.f};
  f32x4 acc[4][4];
#pragma unroll
  for (int i = 0; i < 4; ++i)
#pragma unroll
    for (int j = 0; j < 4; ++j) acc[i][j] = z;

  for (int k0 = 0; k0 < Kd; k0 += 64) {
#pragma unroll
    for (int j = 0; j < 4; ++j) {
      const int slot = j * 256 + tid;
      const int r = slot >> 3, cs = slot & 7;
      const int c = cs ^ (r & 7);  // pre-swizzled global source, linear LDS dest
      gload_lds16(A + (size_t)(m0 + r) * Kd + k0 + c * 8,
                  &lA[j * 256 + wave * 64]);
      gload_lds16(Bt + (size_t)(n0 + r) * Kd + k0 + c * 8,
                  &lB[j * 256 + wave * 64]);
    }
    __syncthreads();
    bf16x8 af[2][4], bfr[2][4];
#pragma unroll
    for (int ks = 0; ks < 2; ++ks) {
#pragma unroll
      for (int i = 0; i < 4; ++i) {
        const int ra = wm * 64 + i * 16 + l15;
        af[ks][i] = lA[ra * 8 + ((ks * 4 + l4) ^ (ra & 7))];
        const int rb = wn * 64 + i * 16 + l15;
        bfr[ks][i] = lB[rb * 8 + ((ks * 4 + l4) ^ (rb & 7))];
      }
    }
#pragma unroll
    for (int ks = 0; ks < 2; ++ks)
#pragma unroll
      for (int i = 0; i < 4; ++i)
#pragma unroll
        for (int j = 0; j < 4; ++j)
          acc[i][j] = mfma16(af[ks][i], bfr[ks][j], acc[i][j]);
    __syncthreads();
  }

  // C row m = m0 + wm*64 + i*16 + l4*4 + r ; col n = n0 + wn*64 + j*16 + l15
#pragma unroll
  for (int i = 0; i < 4; ++i) {
    const int m = m0 + wm * 64 + i * 16 + l4 * 4;
#pragma unroll
    for (int j = 0; j < 4; ++j) {
      const int n = n0 + wn * 64 + j * 16 + l15;
      if (MODE == 1) {
        const float bb = b0[n];
#pragma unroll
        for (int r = 0; r < 4; ++r)
          Of[(size_t)(m + r) * DDIM + n] = acc[i][j][r] + bb;
      } else {
        const int sel = n >> 10, nn = n & 1023;
        const int h = nn >> 6, d = nn & 63;
        const float* bp = sel == 0 ? b0 : (sel == 1 ? b1 : b2);
        const float bb = bp[nn];
        const int b = m >> 11, s = m & 2047;
        if (sel == 2) {
          union {
            bf16 h4[4];
            s16x4 v;
          } u;
#pragma unroll
          for (int r = 0; r < 4; ++r)
            u.h4[r] = __float2bfloat16(acc[i][j][r] + bb);
          *reinterpret_cast<s16x4*>(
              &O2[((size_t)(b * HH + h) * HDIM + d) * SS + s]) = u.v;
        } else {
#pragma unroll
          for (int r = 0; r < 4; ++r) {
            const float val = acc[i][j][r] + bb;
            (sel ? O1 : O0)[((size_t)(b * HH + h) * SS + (s + r)) * HDIM + d] =
                __float2bfloat16(val);
          }
        }
      }
    }
  }
}

// ---------------- fused flash attention (swapped-QK^T layout) --------------
// grid.x = B*H*(S/64); block = 256 (4 waves), wave owns 16 q-rows.
// mfma(K,Q) puts S[k=jj*16+l4*4+r][q=l15] per lane: one q-row per lane ->
//  * bias+mask = 4x f32x4/i32x4 vector loads per step, register-prefetched
//    one step ahead (16 regs, named ping-pong, mask folded at prefetch)
//  * softmax state (m,l) scalar per lane; reduce = lane-local + 2 shfl_xor
//  * NO LDS staging, NO barriers; only per-wave swizzled P scratch (8KB)
// Compiler's register-dep waitcnts do the pipelining (prefetch regs unused
// until next iteration -> their loads stay in flight a full step).
__global__ __launch_bounds__(256, 3) void attn_k(
    const bf16* __restrict__ Qb, const bf16* __restrict__ Kb,
    const bf16* __restrict__ Vt, const float* __restrict__ bias,
    const int* __restrict__ kpm, bf16* __restrict__ ctx) {
  __shared__ unsigned int pl[4 * 512];  // 4 waves x 2KB P scratch
  const int wave = threadIdx.x >> 6, lane = threadIdx.x & 63;
  const int l15 = lane & 15, l4 = lane >> 4;
  const int bid = blockIdx.x;
  const int qblk = bid & 31, bh = bid >> 5;
  const int b = bh >> 4, h = bh & 15;
  const int q0w = qblk * 64 + wave * 16;

  const bf16* Qp = Qb + ((size_t)bh * SS + q0w) * HDIM;
  const bf16* Kp = Kb + (size_t)bh * SS * HDIM;
  const bf16* Vp = Vt + (size_t)bh * HDIM * SS;
  const float* Bp = bias + (size_t)h * SS * SS + (size_t)(q0w + l15) * SS;
  const int* mp = kpm + b * SS;
  unsigned int* plw = pl + wave * 512;

  bf16x8 qf[2];
#pragma unroll
  for (int ks = 0; ks < 2; ++ks)
    qf[ks] = *reinterpret_cast<const bf16x8*>(Qp + (size_t)l15 * HDIM +
                                              ks * 32 + l4 * 8);
  const f32x4 z = {0.f, 0.f, 0.f, 0.f};
  f32x4 o[4];
#pragma unroll
  for (int dd = 0; dd < 4; ++dd) o[dd] = z;
  float mrow = -1e30f, lrow = 0.f;

  // load bias[q=l15][k..k+3] + mask, fold: addend = masked ? -1e30 : bias
  auto ldadd = [&](int kb, f32x4 (&dst)[4]) {
#pragma unroll
    for (int jj = 0; jj < 4; ++jj) {
      const int kc = kb + jj * 16 + l4 * 4;
      f32x4 bv = *reinterpret_cast<const f32x4*>(Bp + kc);
      i32x4 mv = *reinterpret_cast<const i32x4*>(mp + kc);
      f32x4 a;
#pragma unroll
      for (int r = 0; r < 4; ++r) a[r] = mv[r] ? -1e30f : bv[r];
      dst[jj] = a;
    }
  };

  f32x4 addA[4], addB[4];
  ldadd(0, addA);

  auto step = [&](int t, const f32x4 (&cur)[4], f32x4 (&nxt)[4]) {
    const int kb = t * 64;
    const int kbn = (kb + 64) & (SS - 1);
    // 1) prefetch next addend (consumed next step; loads stay in flight)
    ldadd(kbn, nxt);
    // 2) K fragments
    bf16x8 kf[4][2];
#pragma unroll
    for (int jj = 0; jj < 4; ++jj)
#pragma unroll
      for (int ks = 0; ks < 2; ++ks)
        kf[jj][ks] = *reinterpret_cast<const bf16x8*>(
            Kp + (size_t)(kb + jj * 16 + l15) * HDIM + ks * 32 + l4 * 8);
    // 3) swapped QK^T: sc[jj][r] = S[k=kb+jj*16+l4*4+r][q=l15]
    f32x4 sc[4];
#pragma unroll
    for (int jj = 0; jj < 4; ++jj) {
      f32x4 s = z;
#pragma unroll
      for (int ks = 0; ks < 2; ++ks) s = mfma16(kf[jj][ks], qf[ks], s);
      sc[jj] = s;
    }
    // 4) V fragments issued now; latency hides under softmax
    bf16x8 vf[4][2];
#pragma unroll
    for (int dd = 0; dd < 4; ++dd)
#pragma unroll
      for (int ks = 0; ks < 2; ++ks)
        vf[dd][ks] = *reinterpret_cast<const bf16x8*>(
            Vp + (size_t)(dd * 16 + l15) * SS + kb + ks * 32 + l4 * 8);
    // 5) softmax (lane-local row q=l15)
    float v[4][4];
    float bm = -1e30f;
#pragma unroll
    for (int jj = 0; jj < 4; ++jj)
#pragma unroll
      for (int r = 0; r < 4; ++r) {
        v[jj][r] = fmaf(sc[jj][r], 0.125f, cur[jj][r]);
        bm = fmaxf(bm, v[jj][r]);
      }
    bm = fmaxf(bm, __shfl_xor(bm, 16));
    bm = fmaxf(bm, __shfl_xor(bm, 32));
    const float mn = fmaxf(mrow, bm);
    const float alpha = __expf(mrow - mn);
    mrow = mn;
    float ps = 0.f;
    float p[4][4];
#pragma unroll
    for (int jj = 0; jj < 4; ++jj)
#pragma unroll
      for (int r = 0; r < 4; ++r) {
        p[jj][r] = __expf(v[jj][r] - mn);
        ps += p[jj][r];
      }
    ps += __shfl_xor(ps, 16);
    ps += __shfl_xor(ps, 32);
    lrow = lrow * alpha + ps;
    // 6) pack P to per-wave LDS: byte = l15*128 + 2k, k = jj*16+l4*4+r,
    //    XOR-swizzled by ((l15&7)<<4)
#pragma unroll
    for (int jj = 0; jj < 4; ++jj)
#pragma unroll
      for (int r0 = 0; r0 < 4; r0 += 2) {
        union {
          bf16 h2[2];
          unsigned int w;
        } u;
        u.h2[0] = __float2bfloat16(p[jj][r0]);
        u.h2[1] = __float2bfloat16(p[jj][r0 + 1]);
        const int byte =
            (l15 * 128 + jj * 32 + l4 * 8 + r0 * 2) ^ ((l15 & 7) << 4);
        plw[byte >> 2] = u.w;
      }
    // 7) read PV A-fragments: bf16x8 at [l15][ks*32+l4*8]
    bf16x8 pf[2];
#pragma unroll
    for (int ks = 0; ks < 2; ++ks) {
      const int byte = (l15 * 128 + ks * 64 + l4 * 16) ^ ((l15 & 7) << 4);
      pf[ks] = *reinterpret_cast<const bf16x8*>(
          reinterpret_cast<const char*>(plw) + byte);
    }
    // 8) redistribute alpha (per q=l15) to o-layout (q=l4*4+r), rescale, PV
    float ar[4];
#pragma unroll
    for (int r = 0; r < 4; ++r) ar[r] = __shfl(alpha, l4 * 4 + r);
#pragma unroll
    for (int dd = 0; dd < 4; ++dd) {
#pragma unroll
      for (int r = 0; r < 4; ++r) o[dd][r] *= ar[r];
#pragma unroll
      for (int ks = 0; ks < 2; ++ks) o[dd] = mfma16(pf[ks], vf[dd][ks], o[dd]);
    }
  };

  for (int t2 = 0; t2 < 16; ++t2) {
    step(t2 * 2, addA, addB);
    step(t2 * 2 + 1, addB, addA);
  }

  const float rl = 1.0f / lrow;
  float rlr[4];
#pragma unroll
  for (int r = 0; r < 4; ++r) rlr[r] = __shfl(rl, l4 * 4 + r);
#pragma unroll
  for (int dd = 0; dd < 4; ++dd) {
#pragma unroll
    for (int r = 0; r < 4; ++r) {
      const float val = o[dd][r] * rlr[r];
      const int s = q0w + l4 * 4 + r;
      ctx[((size_t)b * SS + s) * DDIM + h * HDIM + dd * 16 + l15] =
          __float2bfloat16(val);
    }
  }
}

extern "C" void kernel_launch(void* const* d_in, const int* in_sizes, int n_in,
                              void* d_out, int out_size, void* d_ws,
                              size_t ws_size, hipStream_t stream) {
  const float* x = (const float*)d_in[0];
  const float* abias = (const float*)d_in[1];
  const int* kpm = (const int*)d_in[2];
  const float* Wq = (const float*)d_in[3];
  const float* bq = (const float*)d_in[4];
  const float* Wk = (const float*)d_in[5];
  const float* bk = (const float*)d_in[6];
  const float* Wv = (const float*)d_in[7];
  const float* bv = (const float*)d_in[8];
  const float* Wo = (const float*)d_in[9];
  const float* bo = (const float*)d_in[10];
  float* out = (float*)d_out;

  char* ws = (char*)d_ws;
  bf16* xb = (bf16*)ws;                        // (B,S,D) bf16      8 MB
  bf16* Wt = (bf16*)(ws + 8388608);            // 3072x1024 bf16    6 MB
  bf16* Wot = (bf16*)(ws + 14680064);          // 1024x1024 bf16    2 MB
  bf16* Qb = (bf16*)(ws + 16777216);           // (B,H,S,HD)        8 MB
  bf16* Kb = (bf16*)(ws + 25165824);           // (B,H,S,HD)        8 MB
  bf16* Vtb = (bf16*)(ws + 33554432);          // (B,H,HD,S)        8 MB
  bf16* ctx = (bf16*)(ws + 41943040);          // (B,S,D) bf16      8 MB

  dim3 t256(256);
  cvt_k<<<dim3(2048), t256, 0, stream>>>(x, xb);
  transpose_cvt_k<<<dim3(16, 16), t256, 0, stream>>>(Wq, Wt);
  transpose_cvt_k<<<dim3(16, 16), t256, 0, stream>>>(Wk, Wt + 1024 * 1024);
  transpose_cvt_k<<<dim3(16, 16), t256, 0, stream>>>(Wv, Wt + 2 * 1024 * 1024);
  transpose_cvt_k<<<dim3(16, 16), t256, 0, stream>>>(Wo, Wot);

  gemm_bt<0><<<dim3(32, 24), t256, 0, stream>>>(xb, Wt, bq, bk, bv, Qb, Kb,
                                                Vtb, nullptr);
  attn_k<<<dim3(1024), t256, 0, stream>>>(Qb, Kb, Vtb, abias, kpm, ctx);
  gemm_bt<1><<<dim3(32, 8), t256, 0, stream>>>(ctx, Wot, bo, nullptr, nullptr,
                                               nullptr, nullptr, nullptr, out);
}